// Round 1
// baseline (445.485 us; speedup 1.0000x reference)
//
#include <hip/hip_runtime.h>

// Problem constants (fixed by reference setup_inputs)
constexpr int B_  = 2;
constexpr int C_  = 64;    // input channels
constexpr int O_  = 64;    // output channels
constexpr int H_  = 128;
constexpr int W_  = 128;
constexpr int HW_ = H_ * W_;          // 16384
constexpr int NPIX_ = B_ * HW_;       // 32768
constexpr float BN_EPS_ = 1e-5f;

// ---------------------------------------------------------------------------
// Kernel A: 3x3 conv producing 18 offset channels + 9 sigmoid(mask) channels.
// Block = 128 threads = 64 pixels x 2 oc-halves (wave-uniform split so weight
// addresses stay scalar).
// ---------------------------------------------------------------------------
template <int OC0, int NOC>
__device__ __forceinline__ void conv_range(const float* __restrict__ xb,
                                           const float* __restrict__ off_w,
                                           const float* __restrict__ off_b,
                                           const float* __restrict__ mask_w,
                                           const float* __restrict__ mask_b,
                                           float* __restrict__ omb,
                                           int h, int w, int hw) {
    float acc[NOC];
#pragma unroll
    for (int i = 0; i < NOC; i++) {
        constexpr int dummy = 0; (void)dummy;
        int oc = OC0 + i;
        acc[i] = (oc < 18) ? off_b[oc] : mask_b[oc - 18];
    }
    for (int c = 0; c < C_; c++) {
        float xv[9];
#pragma unroll
        for (int kh = 0; kh < 3; kh++) {
#pragma unroll
            for (int kw = 0; kw < 3; kw++) {
                int hh = h + kh - 1, ww = w + kw - 1;
                bool ok = (hh >= 0) && (hh < H_) && (ww >= 0) && (ww < W_);
                xv[kh * 3 + kw] = ok ? xb[c * HW_ + hh * W_ + ww] : 0.f;
            }
        }
#pragma unroll
        for (int i = 0; i < NOC; i++) {
            int oc = OC0 + i;
            const float* wr = (oc < 18) ? (off_w + (oc * C_ + c) * 9)
                                        : (mask_w + ((oc - 18) * C_ + c) * 9);
#pragma unroll
            for (int k = 0; k < 9; k++) acc[i] = fmaf(xv[k], wr[k], acc[i]);
        }
    }
#pragma unroll
    for (int i = 0; i < NOC; i++) {
        int oc = OC0 + i;
        float v = acc[i];
        if (oc >= 18) v = 1.f / (1.f + __expf(-v));   // sigmoid for mask chans
        omb[oc * HW_ + hw] = v;
    }
}

__global__ __launch_bounds__(128)
void offmask_kernel(const float* __restrict__ x,
                    const float* __restrict__ off_w, const float* __restrict__ off_b,
                    const float* __restrict__ mask_w, const float* __restrict__ mask_b,
                    float* __restrict__ offm) {
    int tid = threadIdx.x;
    int p = tid & 63;
    int half = __builtin_amdgcn_readfirstlane(tid >> 6);   // wave-uniform
    int pg = blockIdx.x * 64 + p;                          // global pixel
    int b = pg >> 14;                                      // / HW_
    int hw = pg & (HW_ - 1);
    int h = hw >> 7, w = hw & (W_ - 1);
    const float* xb = x + b * C_ * HW_;
    float* omb = offm + b * 27 * HW_;
    if (half == 0) conv_range<0, 14>(xb, off_w, off_b, mask_w, mask_b, omb, h, w, hw);
    else           conv_range<14, 13>(xb, off_w, off_b, mask_w, mask_b, omb, h, w, hw);
}

// ---------------------------------------------------------------------------
// Kernel B: deformable bilinear sampling + einsum over (c,k) + BN stats.
// Block = 256 threads, 64 pixels. Thread (p = tid&63, og = tid>>6) accumulates
// 16 output channels for pixel p. Per input channel c, 64x9 sampled values are
// staged in double-buffered LDS. Sampling metadata lives in registers.
// ---------------------------------------------------------------------------
__global__ __launch_bounds__(256)
void deform_kernel(const float* __restrict__ x,
                   const float* __restrict__ offm,
                   const float* __restrict__ conv_w,   // [O][C][9]
                   float* __restrict__ preout,         // [B][O][H][W]
                   float* __restrict__ stats) {        // [0..63]=sum, [64..127]=sumsq
    __shared__ float vbuf[2][9 * 64];

    const int tid = threadIdx.x;
    const int pbase = blockIdx.x * 64;
    const int b = pbase >> 14;             // block-uniform (64 | HW_)
    const int hwbase = pbase & (HW_ - 1);
    const float* xb = x + b * C_ * HW_;
    const float* omb = offm + b * 27 * HW_;

    // ---- Phase 0: per-thread sampling metadata (items tid, tid+256, tid+512)
    const int nit = (tid < 64) ? 3 : 2;    // 576 items over 256 threads
    int   midx[3][4];
    float mwgt[3][4];
#pragma unroll
    for (int j = 0; j < 3; j++) {
        if (j < nit) {
            int item = tid + j * 256;
            int k = item >> 6, p = item & 63;
            int hw = hwbase + p;
            int h = hw >> 7, w = hw & (W_ - 1);
            float dy = omb[(2 * k) * HW_ + hw];
            float dx = omb[(2 * k + 1) * HW_ + hw];
            float m  = omb[(18 + k) * HW_ + hw];
            float py = dy + (float)(h + (k / 3) - 1);
            float px = dx + (float)(w + (k % 3) - 1);
            float y0 = floorf(py), x0 = floorf(px);
            float ly = py - y0, lx = px - x0;
            float hy = 1.f - ly, hx = 1.f - lx;
            float y1 = y0 + 1.f, x1 = x0 + 1.f;
            bool vy0 = (y0 >= 0.f) && (y0 <= (float)(H_ - 1));
            bool vy1 = (y1 >= 0.f) && (y1 <= (float)(H_ - 1));
            bool vx0 = (x0 >= 0.f) && (x0 <= (float)(W_ - 1));
            bool vx1 = (x1 >= 0.f) && (x1 <= (float)(W_ - 1));
            int iy0 = (int)fminf(fmaxf(y0, 0.f), (float)(H_ - 1));
            int iy1 = (int)fminf(fmaxf(y1, 0.f), (float)(H_ - 1));
            int ix0 = (int)fminf(fmaxf(x0, 0.f), (float)(W_ - 1));
            int ix1 = (int)fminf(fmaxf(x1, 0.f), (float)(W_ - 1));
            midx[j][0] = iy0 * W_ + ix0;  mwgt[j][0] = (vy0 && vx0) ? hy * hx * m : 0.f;
            midx[j][1] = iy0 * W_ + ix1;  mwgt[j][1] = (vy0 && vx1) ? hy * lx * m : 0.f;
            midx[j][2] = iy1 * W_ + ix0;  mwgt[j][2] = (vy1 && vx0) ? ly * hx * m : 0.f;
            midx[j][3] = iy1 * W_ + ix1;  mwgt[j][3] = (vy1 && vx1) ? ly * lx * m : 0.f;
        }
    }

    auto sample_into = [&](float* vb, const float* xp) {
#pragma unroll
        for (int j = 0; j < 3; j++) {
            if (j < nit) {
                float s = mwgt[j][0] * xp[midx[j][0]]
                        + mwgt[j][1] * xp[midx[j][1]]
                        + mwgt[j][2] * xp[midx[j][2]]
                        + mwgt[j][3] * xp[midx[j][3]];
                vb[tid + j * 256] = s;   // layout [k*64 + p]
            }
        }
    };

    // prime c = 0
    sample_into(vbuf[0], xb);
    __syncthreads();

    const int p = tid & 63;
    const int og = __builtin_amdgcn_readfirstlane(tid >> 6);  // wave-uniform o-group
    const float* wbase = conv_w + og * 16 * (C_ * 9);

    float acc[16];
#pragma unroll
    for (int oo = 0; oo < 16; oo++) acc[oo] = 0.f;

    for (int c = 0; c < C_; c++) {
        int cur = c & 1;
        if (c + 1 < C_) sample_into(vbuf[cur ^ 1], xb + (c + 1) * HW_);
        float v[9];
#pragma unroll
        for (int k = 0; k < 9; k++) v[k] = vbuf[cur][k * 64 + p];
#pragma unroll
        for (int oo = 0; oo < 16; oo++) {
            const float* wr = wbase + oo * (C_ * 9) + c * 9;   // scalar (s_load)
            float s = acc[oo];
#pragma unroll
            for (int k = 0; k < 9; k++) s = fmaf(v[k], wr[k], s);
            acc[oo] = s;
        }
        __syncthreads();
    }

    // ---- epilogue: store pre-BN out + per-channel sum/sumsq reduction
    int hw = hwbase + p;
    float* ob = preout + (b * O_ + og * 16) * HW_ + hw;
#pragma unroll
    for (int oo = 0; oo < 16; oo++) {
        float a = acc[oo];
        ob[oo * HW_] = a;
        float s = a, s2 = a * a;
#pragma unroll
        for (int off = 32; off >= 1; off >>= 1) {
            s  += __shfl_down(s, off);
            s2 += __shfl_down(s2, off);
        }
        if (p == 0) {
            atomicAdd(&stats[og * 16 + oo], s);
            atomicAdd(&stats[64 + og * 16 + oo], s2);
        }
    }
}

// ---------------------------------------------------------------------------
// Kernel C: BN (batch stats) + ReLU. Each block covers 1024 contiguous floats
// (single channel), computes scale/shift inline from stats.
// ---------------------------------------------------------------------------
__global__ __launch_bounds__(256)
void bn_relu_kernel(const float* __restrict__ preout,
                    const float* __restrict__ stats,
                    const float* __restrict__ gamma,
                    const float* __restrict__ beta,
                    float* __restrict__ out) {
    int i = blockIdx.x * 256 + threadIdx.x;      // float4 index, 524288 total
    int ch = (i >> 12) & (O_ - 1);               // (i*4 / HW_) % O_
    float mean = stats[ch] * (1.f / NPIX_);
    float var  = stats[64 + ch] * (1.f / NPIX_) - mean * mean;
    float scale = gamma[ch] * rsqrtf(var + BN_EPS_);
    float shift = beta[ch] - mean * scale;
    float4 v = reinterpret_cast<const float4*>(preout)[i];
    v.x = fmaxf(fmaf(v.x, scale, shift), 0.f);
    v.y = fmaxf(fmaf(v.y, scale, shift), 0.f);
    v.z = fmaxf(fmaf(v.z, scale, shift), 0.f);
    v.w = fmaxf(fmaf(v.w, scale, shift), 0.f);
    reinterpret_cast<float4*>(out)[i] = v;
}

// ---------------------------------------------------------------------------
extern "C" void kernel_launch(void* const* d_in, const int* in_sizes, int n_in,
                              void* d_out, int out_size, void* d_ws, size_t ws_size,
                              hipStream_t stream) {
    const float* x      = (const float*)d_in[0];
    const float* conv_w = (const float*)d_in[1];
    const float* off_w  = (const float*)d_in[2];
    const float* off_b  = (const float*)d_in[3];
    const float* mask_w = (const float*)d_in[4];
    const float* mask_b = (const float*)d_in[5];
    const float* gamma  = (const float*)d_in[6];
    const float* beta   = (const float*)d_in[7];
    float* out = (float*)d_out;

    char* ws = (char*)d_ws;
    float* preout = (float*)ws;                                   // 2,097,152 f
    float* offm   = (float*)(ws + (size_t)B_ * O_ * HW_ * 4);     // 884,736 f
    float* stats  = (float*)(ws + (size_t)(B_ * O_ * HW_ + B_ * 27 * HW_) * 4);

    hipMemsetAsync(stats, 0, 128 * sizeof(float), stream);

    offmask_kernel<<<NPIX_ / 64, 128, 0, stream>>>(x, off_w, off_b, mask_w, mask_b, offm);
    deform_kernel<<<NPIX_ / 64, 256, 0, stream>>>(x, offm, conv_w, preout, stats);
    bn_relu_kernel<<<(B_ * O_ * HW_ / 4) / 256, 256, 0, stream>>>(preout, stats, gamma, beta, out);
}

// Round 3
// 172.658 us; speedup vs baseline: 2.5802x; 2.5802x over previous
//
#include <hip/hip_runtime.h>

typedef __attribute__((ext_vector_type(8))) short bf16x8;
typedef __attribute__((ext_vector_type(4))) float f32x4;
typedef unsigned int  u32;
typedef unsigned short u16;

constexpr int B_  = 2;
constexpr int C_  = 64;
constexpr int O_  = 64;
constexpr int H_  = 128;
constexpr int W_  = 128;
constexpr int HW_ = H_ * W_;          // 16384
constexpr int NPIX_ = B_ * HW_;       // 32768
constexpr int KK_ = 576;              // 9 taps * 64 channels, permuted kk = k*64 + c
constexpr float BN_EPS_ = 1e-5f;

__device__ __forceinline__ u16 f2bf(float f) {
    u32 u = __float_as_uint(f);
    u = (u + 0x7fffu + ((u >> 16) & 1u)) >> 16;   // RNE
    return (u16)u;
}
__device__ __forceinline__ float bflo(u32 u) { return __uint_as_float(u << 16); }
__device__ __forceinline__ float bfhi(u32 u) { return __uint_as_float(u & 0xffff0000u); }

// ---------------------------------------------------------------------------
// prep: permuted bf16 weights (kk = k*64 + c) + stats zero.
//   Wp  [64][576] : Wp[o][k*64+c]  = conv_w[o][c][k]
//   W27p[32][576] : rows 0-17 off_w, 18-26 mask_w, 27-31 zero (same kk perm)
// ---------------------------------------------------------------------------
__global__ __launch_bounds__(256)
void prep_kernel(const float* __restrict__ conv_w, const float* __restrict__ off_w,
                 const float* __restrict__ mask_w, u16* __restrict__ Wp,
                 u16* __restrict__ W27p, float* __restrict__ stats) {
    int bid = blockIdx.x, tid = threadIdx.x;
    if (bid < 144) {                        // 64*576 = 36864
        int i = bid * 256 + tid;
        int o = i / KK_, rem = i - o * KK_;
        int k = rem >> 6, c = rem & 63;
        Wp[i] = f2bf(conv_w[(o * 64 + c) * 9 + k]);
    } else if (bid < 216) {                 // 32*576 = 18432
        int i = (bid - 144) * 256 + tid;
        int row = i / KK_, rem = i - row * KK_;
        int k = rem >> 6, c = rem & 63;
        float v = 0.f;
        if (row < 18) v = off_w[(row * 64 + c) * 9 + k];
        else if (row < 27) v = mask_w[((row - 18) * 64 + c) * 9 + k];
        W27p[i] = f2bf(v);
    } else {
        if (tid < 128) stats[tid] = 0.f;
    }
}

// ---------------------------------------------------------------------------
// GEMM-a (fused im2col): offm[b][o][hw], o<27 = W27p x im2col(x), +bias,
// sigmoid on mask rows. Block 256 thr / 64 pixels. Wave wv: o-rows
// (wv&1)*16..+16, pixel half (wv>>1)*32..+32. K-step s = (tap s>>1, 32 chans).
// Staging: thread (sp=tid&63, g=tid>>6) computes 8 values (c = c0+g*8+j).
// ---------------------------------------------------------------------------
__global__ __launch_bounds__(256)
void gemm_a_fused(const float* __restrict__ x, const u16* __restrict__ W27p,
                  const float* __restrict__ off_b, const float* __restrict__ mask_b,
                  float* __restrict__ offm) {
    __shared__ __align__(16) u16 Bt[2][64 * 32];
    const int tid = threadIdx.x;
    const int pbase = blockIdx.x * 64;
    const int b = pbase >> 14, hwb = pbase & (HW_ - 1);
    const float* xb = x + (size_t)b * C_ * HW_;

    // staging identity
    const int sp = tid & 63, g = tid >> 6;
    const int shw = hwb + sp, sh = shw >> 7, sw = shw & (W_ - 1);
    int sidx[9]; float svf[9];
#pragma unroll
    for (int k = 0; k < 9; k++) {
        int hh = sh + k / 3 - 1, ww = sw + k % 3 - 1;
        bool ok = (hh >= 0) && (hh < H_) && (ww >= 0) && (ww < W_);
        sidx[k] = ok ? hh * W_ + ww : 0;
        svf[k] = ok ? 1.f : 0.f;
    }

    // mfma identity
    const int lane = tid & 63, wv = tid >> 6;
    const int quad = lane >> 4, r = lane & 15;
    const int orow = (wv & 1) * 16 + r;
    const int phalf = (wv >> 1) * 32;
    bf16x8 afr[18];
    const u16* wrow = W27p + orow * KK_ + quad * 8;
#pragma unroll
    for (int s = 0; s < 18; s++) afr[s] = *(const bf16x8*)(wrow + s * 32);

    f32x4 acc[2];
    acc[0] = (f32x4){0.f, 0.f, 0.f, 0.f};
    acc[1] = (f32x4){0.f, 0.f, 0.f, 0.f};

#pragma unroll
    for (int s = 0; s < 18; s++) {
        const int k = s >> 1;
        const float* xc = xb + (size_t)((s & 1) * 32 + g * 8) * HW_ + sidx[k];
        bf16x8 sv;
#pragma unroll
        for (int j = 0; j < 8; j++) sv[j] = (short)f2bf(xc[(size_t)j * HW_] * svf[k]);
        *(bf16x8*)(&Bt[s & 1][sp * 32 + g * 8]) = sv;
        __syncthreads();
#pragma unroll
        for (int i = 0; i < 2; i++) {
            bf16x8 bfr = *(const bf16x8*)(&Bt[s & 1][(phalf + i * 16 + r) * 32 + quad * 8]);
            acc[i] = __builtin_amdgcn_mfma_f32_16x16x32_bf16(afr[s], bfr, acc[i], 0, 0, 0);
        }
        // next iter writes the other buffer; writes to this one recur at s+2
        // after the s+1 barrier, by which time all reads here have completed.
    }

#pragma unroll
    for (int g2 = 0; g2 < 4; g2++) {
        int o = (wv & 1) * 16 + quad * 4 + g2;
        if (o < 27) {
#pragma unroll
            for (int i = 0; i < 2; i++) {
                float v = acc[i][g2];
                int hw2 = hwb + phalf + i * 16 + r;
                if (o < 18) v += off_b[o];
                else { v += mask_b[o - 18]; v = 1.f / (1.f + __expf(-v)); }
                offm[((size_t)b * 27 + o) * HW_ + hw2] = v;
            }
        }
    }
}

// ---------------------------------------------------------------------------
// GEMM-b (fused bilinear sampler): pre16 = Wp x sampled(x, offm), bf16 out,
// fp32 BN stats via width-16 shuffle + atomics. Block 256 thr / 64 pixels.
// Phase 0 precomputes per-(tap,pixel) 4 corner idx + 4 modulated weights
// into LDS; K-loop gathers 4 fp32 corners per (c,p,tap) and feeds MFMA.
// ---------------------------------------------------------------------------
__global__ __launch_bounds__(256)
void gemm_b_fused(const float* __restrict__ x, const float* __restrict__ offm,
                  const u16* __restrict__ Wp, u16* __restrict__ pre16,
                  float* __restrict__ stats) {
    __shared__ __align__(16) int   midx[9 * 64 * 4];
    __shared__ __align__(16) float mwgt[9 * 64 * 4];
    __shared__ __align__(16) u16   Bt[2][64 * 32];
    const int tid = threadIdx.x;
    const int pbase = blockIdx.x * 64;
    const int b = pbase >> 14, hwb = pbase & (HW_ - 1);
    const float* xb = x + (size_t)b * C_ * HW_;
    const float* omb = offm + (size_t)b * 27 * HW_;

    // ---- phase 0: sampling metadata for 576 (tap,pixel) items
    const int nit = (tid < 64) ? 3 : 2;
#pragma unroll
    for (int j = 0; j < 3; j++) {
        if (j < nit) {
            int item = tid + j * 256;
            int k = item >> 6, p = item & 63;
            int hw = hwb + p, h = hw >> 7, w = hw & (W_ - 1);
            float dy = omb[(2 * k) * HW_ + hw];
            float dx = omb[(2 * k + 1) * HW_ + hw];
            float m  = omb[(18 + k) * HW_ + hw];
            float py = dy + (float)(h + k / 3 - 1);
            float px = dx + (float)(w + k % 3 - 1);
            float y0 = floorf(py), x0 = floorf(px);
            float ly = py - y0, lx = px - x0;
            float hy = 1.f - ly, hx = 1.f - lx;
            float y1 = y0 + 1.f, x1 = x0 + 1.f;
            bool vy0 = (y0 >= 0.f) && (y0 <= (float)(H_ - 1));
            bool vy1 = (y1 >= 0.f) && (y1 <= (float)(H_ - 1));
            bool vx0 = (x0 >= 0.f) && (x0 <= (float)(W_ - 1));
            bool vx1 = (x1 >= 0.f) && (x1 <= (float)(W_ - 1));
            int iy0 = (int)fminf(fmaxf(y0, 0.f), (float)(H_ - 1));
            int iy1 = (int)fminf(fmaxf(y1, 0.f), (float)(H_ - 1));
            int ix0 = (int)fminf(fmaxf(x0, 0.f), (float)(W_ - 1));
            int ix1 = (int)fminf(fmaxf(x1, 0.f), (float)(W_ - 1));
            int base = (k * 64 + p) * 4;
            midx[base + 0] = iy0 * W_ + ix0;  mwgt[base + 0] = (vy0 && vx0) ? hy * hx * m : 0.f;
            midx[base + 1] = iy0 * W_ + ix1;  mwgt[base + 1] = (vy0 && vx1) ? hy * lx * m : 0.f;
            midx[base + 2] = iy1 * W_ + ix0;  mwgt[base + 2] = (vy1 && vx0) ? ly * hx * m : 0.f;
            midx[base + 3] = iy1 * W_ + ix1;  mwgt[base + 3] = (vy1 && vx1) ? ly * lx * m : 0.f;
        }
    }
    __syncthreads();

    const int sp = tid & 63, g = tid >> 6;
    const int lane = tid & 63, wv = tid >> 6;
    const int quad = lane >> 4, r = lane & 15;
    bf16x8 afr[18];
    const u16* wrow = Wp + (wv * 16 + r) * KK_ + quad * 8;
#pragma unroll
    for (int s = 0; s < 18; s++) afr[s] = *(const bf16x8*)(wrow + s * 32);

    f32x4 acc[4];
#pragma unroll
    for (int i = 0; i < 4; i++) acc[i] = (f32x4){0.f, 0.f, 0.f, 0.f};

#pragma unroll
    for (int s = 0; s < 18; s++) {
        const int k = s >> 1;
        int4   ii = ((const int4*)midx)[k * 64 + sp];
        float4 wt = ((const float4*)mwgt)[k * 64 + sp];
        const float* xc = xb + (size_t)((s & 1) * 32 + g * 8) * HW_;
        bf16x8 sv;
#pragma unroll
        for (int j = 0; j < 8; j++) {
            const float* xj = xc + (size_t)j * HW_;
            float v = wt.x * xj[ii.x] + wt.y * xj[ii.y]
                    + wt.z * xj[ii.z] + wt.w * xj[ii.w];
            sv[j] = (short)f2bf(v);
        }
        *(bf16x8*)(&Bt[s & 1][sp * 32 + g * 8]) = sv;
        __syncthreads();
#pragma unroll
        for (int i = 0; i < 4; i++) {
            bf16x8 bfr = *(const bf16x8*)(&Bt[s & 1][(i * 16 + r) * 32 + quad * 8]);
            acc[i] = __builtin_amdgcn_mfma_f32_16x16x32_bf16(afr[s], bfr, acc[i], 0, 0, 0);
        }
    }

    // ---- epilogue: bf16 pre-out + fp32 stats (reduce over 16 pixel-lanes)
#pragma unroll
    for (int g2 = 0; g2 < 4; g2++) {
        int o = wv * 16 + quad * 4 + g2;
        float ssum = 0.f, ssq = 0.f;
#pragma unroll
        for (int i = 0; i < 4; i++) {
            float v = acc[i][g2];
            pre16[((size_t)(b * O_ + o)) * HW_ + hwb + i * 16 + r] = f2bf(v);
            ssum += v; ssq += v * v;
        }
#pragma unroll
        for (int off = 8; off >= 1; off >>= 1) {
            ssum += __shfl_down(ssum, off, 16);
            ssq  += __shfl_down(ssq, off, 16);
        }
        if (r == 0) {
            atomicAdd(&stats[o], ssum);
            atomicAdd(&stats[64 + o], ssq);
        }
    }
}

// ---------------------------------------------------------------------------
// BN apply + ReLU from bf16 pre-out.
// ---------------------------------------------------------------------------
__global__ __launch_bounds__(256)
void bn_relu_kernel(const u16* __restrict__ pre16, const float* __restrict__ stats,
                    const float* __restrict__ gamma, const float* __restrict__ beta,
                    float* __restrict__ out) {
    int i4 = blockIdx.x * 256 + threadIdx.x;   // 4-element group index
    int ch = (i4 >> 12) & (O_ - 1);            // ((i4*4) / HW_) % 64
    float mean = stats[ch] * (1.f / NPIX_);
    float var  = stats[64 + ch] * (1.f / NPIX_) - mean * mean;
    float scale = gamma[ch] * rsqrtf(var + BN_EPS_);
    float shift = beta[ch] - mean * scale;
    uint2 v = ((const uint2*)pre16)[i4];
    float4 o;
    o.x = fmaxf(fmaf(bflo(v.x), scale, shift), 0.f);
    o.y = fmaxf(fmaf(bfhi(v.x), scale, shift), 0.f);
    o.z = fmaxf(fmaf(bflo(v.y), scale, shift), 0.f);
    o.w = fmaxf(fmaf(bfhi(v.y), scale, shift), 0.f);
    ((float4*)out)[i4] = o;
}

// ---------------------------------------------------------------------------
extern "C" void kernel_launch(void* const* d_in, const int* in_sizes, int n_in,
                              void* d_out, int out_size, void* d_ws, size_t ws_size,
                              hipStream_t stream) {
    const float* x      = (const float*)d_in[0];
    const float* conv_w = (const float*)d_in[1];
    const float* off_w  = (const float*)d_in[2];
    const float* off_b  = (const float*)d_in[3];
    const float* mask_w = (const float*)d_in[4];
    const float* mask_b = (const float*)d_in[5];
    const float* gamma  = (const float*)d_in[6];
    const float* beta   = (const float*)d_in[7];
    float* out = (float*)d_out;

    // workspace: 7,844,352 B total (round-1's 11.9 MB usage proved safe)
    char* ws = (char*)d_ws;
    float* offm  = (float*)(ws);                 // [2][27][16384] f32 = 3,538,944 B
    u16*  pre16  = (u16*)(ws + 3538944);         // [2][64][16384] bf16 = 4,194,304 B
    u16*  Wp     = (u16*)(ws + 7733248);         // [64][576] = 73,728 B
    u16*  W27p   = (u16*)(ws + 7806976);         // [32][576] = 36,864 B
    float* stats = (float*)(ws + 7843840);       // 512 B

    prep_kernel<<<217, 256, 0, stream>>>(conv_w, off_w, mask_w, Wp, W27p, stats);
    gemm_a_fused<<<NPIX_ / 64, 256, 0, stream>>>(x, W27p, off_b, mask_b, offm);
    gemm_b_fused<<<NPIX_ / 64, 256, 0, stream>>>(x, offm, Wp, pre16, stats);
    bn_relu_kernel<<<2048, 256, 0, stream>>>(pre16, stats, gamma, beta, out);
}

// Round 4
// 148.237 us; speedup vs baseline: 3.0052x; 1.1647x over previous
//
#include <hip/hip_runtime.h>
#include <hip/hip_fp16.h>

typedef __attribute__((ext_vector_type(8))) short bf16x8;
typedef __attribute__((ext_vector_type(4))) float f32x4;
typedef unsigned int  u32;
typedef unsigned short u16;

constexpr int B_  = 2;
constexpr int C_  = 64;
constexpr int O_  = 64;
constexpr int H_  = 128;
constexpr int W_  = 128;
constexpr int HW_ = H_ * W_;          // 16384
constexpr int NPIX_ = B_ * HW_;       // 32768
constexpr float BN_EPS_ = 1e-5f;

__device__ __forceinline__ u16 f2bf(float f) {
    u32 u = __float_as_uint(f);
    u = (u + 0x7fffu + ((u >> 16) & 1u)) >> 16;   // RNE
    return (u16)u;
}
__device__ __forceinline__ float bf2f(u16 v) { return __uint_as_float(((u32)v) << 16); }
__device__ __forceinline__ u16 f2h(float f) { return __half_as_ushort(__float2half(f)); }
__device__ __forceinline__ float h2f(u16 v) { return __half2float(__ushort_as_half(v)); }

// ---------------------------------------------------------------------------
// prep: bf16 copy of x + fragment-linear bf16 weights.
//  xb16[b][c][hw]                        (kk permutation: kk = tap*64 + c)
//  WpF [sg][t][lane][8] : A-frag for o-tile t (o=t*16+(lane&15)), K-step sg,
//                         k-elems kk = sg*32 + (lane>>4)*8 + j
//  W27F[sg][t][lane][8] : same for the 27-row offset/mask matrix (t=0,1)
// ---------------------------------------------------------------------------
__global__ __launch_bounds__(256)
void prep_kernel(const float* __restrict__ x, const float* __restrict__ conv_w,
                 const float* __restrict__ off_w, const float* __restrict__ mask_w,
                 u16* __restrict__ xb16, u16* __restrict__ WpF, u16* __restrict__ W27F) {
    int bid = blockIdx.x, tid = threadIdx.x;
    if (bid < 1024) {                       // 2,097,152 x elements, 8 per thread
        u32 i8 = (u32)(bid * 256 + tid) * 8u;
        float4 a = ((const float4*)x)[i8 >> 2];
        float4 b = ((const float4*)x)[(i8 >> 2) + 1];
        bf16x8 o8;
        o8[0] = (short)f2bf(a.x); o8[1] = (short)f2bf(a.y);
        o8[2] = (short)f2bf(a.z); o8[3] = (short)f2bf(a.w);
        o8[4] = (short)f2bf(b.x); o8[5] = (short)f2bf(b.y);
        o8[6] = (short)f2bf(b.z); o8[7] = (short)f2bf(b.w);
        *(bf16x8*)(xb16 + i8) = o8;
    } else if (bid < 1024 + 144) {          // WpF: 36,864 elements
        int i = (bid - 1024) * 256 + tid;
        int j = i & 7, lane = (i >> 3) & 63, t = (i >> 9) & 3, s = i >> 11;
        int o = t * 16 + (lane & 15);
        int kk = s * 32 + (lane >> 4) * 8 + j;
        int tap = kk >> 6, c = kk & 63;
        WpF[i] = f2bf(conv_w[(o * 64 + c) * 9 + tap]);
    } else {                                // W27F: 18,432 elements
        int i = (bid - 1168) * 256 + tid;
        int j = i & 7, lane = (i >> 3) & 63, t = (i >> 9) & 1, s = i >> 10;
        int row = t * 16 + (lane & 15);
        int kk = s * 32 + (lane >> 4) * 8 + j;
        int tap = kk >> 6, c = kk & 63;
        float v = 0.f;
        if (row < 18) v = off_w[(row * 64 + c) * 9 + tap];
        else if (row < 27) v = mask_w[((row - 18) * 64 + c) * 9 + tap];
        W27F[i] = f2bf(v);
    }
}

// ---------------------------------------------------------------------------
// GEMM-a (fused im2col), barrier-free K-loop. Block 384 thr = 6 waves =
// (2 px-groups of 16) x (3 K-thirds of 6 steps). Lane (quad,r): px = r-col,
// c = quad*8+j — staged values ARE the B-fragment. A from W27F (coalesced).
// End: LDS reduce K-thirds, +bias, sigmoid on mask rows, f16 stores.
// ---------------------------------------------------------------------------
template<int TAP>
__device__ __forceinline__ void metaA(int h, int w, u32 qb, u32& ibase, bool& valid) {
    constexpr int dh = TAP / 3 - 1, dw = TAP % 3 - 1;
    int hh = h + dh, ww = w + dw;
    valid = (hh >= 0) && (hh < H_) && (ww >= 0) && (ww < W_);
    ibase = qb + (valid ? (u32)(hh * W_ + ww) : 0u);
}

template<int SG>
__device__ __forceinline__ void stepA(const u16* __restrict__ xb16,
                                      const u16* __restrict__ W27F, int lane,
                                      u32 ibase, bool valid, f32x4 (&acc)[2]) {
    constexpr u32 CH = (u32)(SG & 1) * 32u;
    bf16x8 sv;
#pragma unroll
    for (int j = 0; j < 8; j++) {
        u16 v = xb16[ibase + ((CH + (u32)j) << 14)];
        sv[j] = valid ? (short)v : (short)0;
    }
#pragma unroll
    for (int t = 0; t < 2; t++) {
        bf16x8 af = *(const bf16x8*)(W27F + (u32)((SG * 2 + t) * 64 + lane) * 8u);
        acc[t] = __builtin_amdgcn_mfma_f32_16x16x32_bf16(af, sv, acc[t], 0, 0, 0);
    }
}

template<int KH>
__device__ __forceinline__ void runA(const u16* __restrict__ xb16,
                                     const u16* __restrict__ W27F,
                                     int h, int w, u32 qb, int lane, f32x4 (&acc)[2]) {
    u32 ib; bool vl;
    metaA<3 * KH + 0>(h, w, qb, ib, vl);
    stepA<6 * KH + 0>(xb16, W27F, lane, ib, vl, acc);
    stepA<6 * KH + 1>(xb16, W27F, lane, ib, vl, acc);
    metaA<3 * KH + 1>(h, w, qb, ib, vl);
    stepA<6 * KH + 2>(xb16, W27F, lane, ib, vl, acc);
    stepA<6 * KH + 3>(xb16, W27F, lane, ib, vl, acc);
    metaA<3 * KH + 2>(h, w, qb, ib, vl);
    stepA<6 * KH + 4>(xb16, W27F, lane, ib, vl, acc);
    stepA<6 * KH + 5>(xb16, W27F, lane, ib, vl, acc);
}

__global__ __launch_bounds__(384, 4)
void gemm_a_kernel(const u16* __restrict__ xb16, const u16* __restrict__ W27F,
                   const float* __restrict__ off_b, const float* __restrict__ mask_b,
                   u16* __restrict__ off16, u16* __restrict__ mask16) {
    __shared__ float red[4][64][9];
    const int tid = threadIdx.x;
    const int lane = tid & 63, wv = tid >> 6;
    const int ph = wv & 1, kh = wv >> 1;
    const int quad = lane >> 4, r = lane & 15;
    const int pbase = blockIdx.x * 32;
    const int b = pbase >> 14, hwb = pbase & (HW_ - 1);
    const int hw = hwb + ph * 16 + r, h = hw >> 7, w = hw & (W_ - 1);
    const u32 qb = ((u32)(b * 64 + quad * 8)) << 14;

    f32x4 acc[2];
    acc[0] = (f32x4){0.f, 0.f, 0.f, 0.f};
    acc[1] = (f32x4){0.f, 0.f, 0.f, 0.f};

    if (kh == 0)      runA<0>(xb16, W27F, h, w, qb, lane, acc);
    else if (kh == 1) runA<1>(xb16, W27F, h, w, qb, lane, acc);
    else              runA<2>(xb16, W27F, h, w, qb, lane, acc);

    if (kh != 0) {
        int slot = (kh - 1) * 2 + ph;
#pragma unroll
        for (int t = 0; t < 2; t++)
#pragma unroll
            for (int g = 0; g < 4; g++) red[slot][lane][t * 4 + g] = acc[t][g];
    }
    __syncthreads();
    if (kh == 0) {
#pragma unroll
        for (int t = 0; t < 2; t++) {
#pragma unroll
            for (int g = 0; g < 4; g++) {
                float v = acc[t][g] + red[ph][lane][t * 4 + g] + red[2 + ph][lane][t * 4 + g];
                int o = t * 16 + quad * 4 + g;
                if (o < 18) {
                    v += off_b[o];
                    off16[(u32)(b * 18 + o) * HW_ + hw] = f2h(v);
                } else if (o < 27) {
                    v += mask_b[o - 18];
                    v = 1.f / (1.f + __expf(-v));
                    mask16[(u32)(b * 9 + (o - 18)) * HW_ + hw] = f2h(v);
                }
            }
        }
    }
}

// ---------------------------------------------------------------------------
// GEMM-b (fused bilinear sampler), barrier-free K-loop, same skeleton.
// Lane computes its own 4-corner metadata per tap (taps 3*KH..3*KH+2).
// Epilogue: LDS reduce, bf16 pre-out, per-block stats partials (no atomics).
// ---------------------------------------------------------------------------
template<int TAP>
__device__ __forceinline__ void metaB(const u16* __restrict__ off16,
                                      const u16* __restrict__ mask16,
                                      int b, int hw, int h, int w, u32 qb,
                                      u32 (&qc)[4], float (&cw)[4]) {
    float dy = h2f(off16[(u32)(b * 18 + 2 * TAP) * HW_ + hw]);
    float dx = h2f(off16[(u32)(b * 18 + 2 * TAP + 1) * HW_ + hw]);
    float m  = h2f(mask16[(u32)(b * 9 + TAP) * HW_ + hw]);
    constexpr float kdy = (float)(TAP / 3 - 1), kdx = (float)(TAP % 3 - 1);
    float py = dy + (float)h + kdy;
    float px = dx + (float)w + kdx;
    float y0 = floorf(py), x0 = floorf(px);
    float ly = py - y0, lx = px - x0, hy = 1.f - ly, hx = 1.f - lx;
    float y1 = y0 + 1.f, x1 = x0 + 1.f;
    bool vy0 = (y0 >= 0.f) && (y0 <= 127.f);
    bool vy1 = (y1 >= 0.f) && (y1 <= 127.f);
    bool vx0 = (x0 >= 0.f) && (x0 <= 127.f);
    bool vx1 = (x1 >= 0.f) && (x1 <= 127.f);
    int iy0 = (int)fminf(fmaxf(y0, 0.f), 127.f);
    int iy1 = (int)fminf(fmaxf(y1, 0.f), 127.f);
    int ix0 = (int)fminf(fmaxf(x0, 0.f), 127.f);
    int ix1 = (int)fminf(fmaxf(x1, 0.f), 127.f);
    qc[0] = qb + (u32)(iy0 * W_ + ix0); cw[0] = (vy0 && vx0) ? hy * hx * m : 0.f;
    qc[1] = qb + (u32)(iy0 * W_ + ix1); cw[1] = (vy0 && vx1) ? hy * lx * m : 0.f;
    qc[2] = qb + (u32)(iy1 * W_ + ix0); cw[2] = (vy1 && vx0) ? ly * hx * m : 0.f;
    qc[3] = qb + (u32)(iy1 * W_ + ix1); cw[3] = (vy1 && vx1) ? ly * lx * m : 0.f;
}

template<int SG>
__device__ __forceinline__ void stepB(const u16* __restrict__ xb16,
                                      const u16* __restrict__ WpF, int lane,
                                      const u32 (&qc)[4], const float (&cw)[4],
                                      f32x4 (&acc)[4]) {
    constexpr u32 CH = (u32)(SG & 1) * 32u;
    bf16x8 sv;
#pragma unroll
    for (int j = 0; j < 8; j++) {
        const u32 sc = (CH + (u32)j) << 14;
        float v = cw[0] * bf2f(xb16[qc[0] + sc]) + cw[1] * bf2f(xb16[qc[1] + sc])
                + cw[2] * bf2f(xb16[qc[2] + sc]) + cw[3] * bf2f(xb16[qc[3] + sc]);
        sv[j] = (short)f2bf(v);
    }
#pragma unroll
    for (int t = 0; t < 4; t++) {
        bf16x8 af = *(const bf16x8*)(WpF + (u32)((SG * 4 + t) * 64 + lane) * 8u);
        acc[t] = __builtin_amdgcn_mfma_f32_16x16x32_bf16(af, sv, acc[t], 0, 0, 0);
    }
}

template<int KH>
__device__ __forceinline__ void runB(const u16* __restrict__ xb16,
                                     const u16* __restrict__ off16,
                                     const u16* __restrict__ mask16,
                                     const u16* __restrict__ WpF,
                                     int b, int hw, int h, int w, u32 qb, int lane,
                                     f32x4 (&acc)[4]) {
    u32 qc[4]; float cw[4];
    metaB<3 * KH + 0>(off16, mask16, b, hw, h, w, qb, qc, cw);
    stepB<6 * KH + 0>(xb16, WpF, lane, qc, cw, acc);
    stepB<6 * KH + 1>(xb16, WpF, lane, qc, cw, acc);
    metaB<3 * KH + 1>(off16, mask16, b, hw, h, w, qb, qc, cw);
    stepB<6 * KH + 2>(xb16, WpF, lane, qc, cw, acc);
    stepB<6 * KH + 3>(xb16, WpF, lane, qc, cw, acc);
    metaB<3 * KH + 2>(off16, mask16, b, hw, h, w, qb, qc, cw);
    stepB<6 * KH + 4>(xb16, WpF, lane, qc, cw, acc);
    stepB<6 * KH + 5>(xb16, WpF, lane, qc, cw, acc);
}

__global__ __launch_bounds__(384, 4)
void gemm_b_kernel(const u16* __restrict__ xb16, const u16* __restrict__ off16,
                   const u16* __restrict__ mask16, const u16* __restrict__ WpF,
                   u16* __restrict__ pre16, float* __restrict__ part) {
    __shared__ float red[4][64][17];
    const int tid = threadIdx.x;
    const int lane = tid & 63, wv = tid >> 6;
    const int ph = wv & 1, kh = wv >> 1;
    const int quad = lane >> 4, r = lane & 15;
    const int pbase = blockIdx.x * 32;
    const int b = pbase >> 14, hwb = pbase & (HW_ - 1);
    const int hw = hwb + ph * 16 + r, h = hw >> 7, w = hw & (W_ - 1);
    const u32 qb = ((u32)(b * 64 + quad * 8)) << 14;

    f32x4 acc[4];
#pragma unroll
    for (int t = 0; t < 4; t++) acc[t] = (f32x4){0.f, 0.f, 0.f, 0.f};

    if (kh == 0)      runB<0>(xb16, off16, mask16, WpF, b, hw, h, w, qb, lane, acc);
    else if (kh == 1) runB<1>(xb16, off16, mask16, WpF, b, hw, h, w, qb, lane, acc);
    else              runB<2>(xb16, off16, mask16, WpF, b, hw, h, w, qb, lane, acc);

    if (kh != 0) {
        int slot = (kh - 1) * 2 + ph;
#pragma unroll
        for (int t = 0; t < 4; t++)
#pragma unroll
            for (int g = 0; g < 4; g++) red[slot][lane][t * 4 + g] = acc[t][g];
    }
    __syncthreads();
    if (kh == 0) {
        float* psum = part + (u32)(blockIdx.x * 2 + ph) * 64;
        float* psq  = part + 131072 + (u32)(blockIdx.x * 2 + ph) * 64;
#pragma unroll
        for (int t = 0; t < 4; t++) {
#pragma unroll
            for (int g = 0; g < 4; g++) {
                float v = acc[t][g] + red[ph][lane][t * 4 + g] + red[2 + ph][lane][t * 4 + g];
                int o = t * 16 + quad * 4 + g;
                pre16[(u32)(b * 64 + o) * HW_ + hw] = f2bf(v);
                float s = v, s2 = v * v;
#pragma unroll
                for (int off = 8; off >= 1; off >>= 1) {
                    s  += __shfl_down(s, off, 16);
                    s2 += __shfl_down(s2, off, 16);
                }
                if (r == 0) { psum[o] = s; psq[o] = s2; }
            }
        }
    }
}

// ---------------------------------------------------------------------------
// stats reduce: 128 stats, each = sum of 2048 block-partials.
// ---------------------------------------------------------------------------
__global__ __launch_bounds__(256)
void stats_red_kernel(const float* __restrict__ part, float* __restrict__ stats) {
    __shared__ float p4[4];
    int i = blockIdx.x;                       // 0..127
    const float* src = part + (u32)(i >> 6) * 131072 + (i & 63);
    float s = 0.f;
    for (int rr = threadIdx.x; rr < 2048; rr += 256) s += src[(u32)rr * 64];
#pragma unroll
    for (int off = 32; off >= 1; off >>= 1) s += __shfl_down(s, off);
    if ((threadIdx.x & 63) == 0) p4[threadIdx.x >> 6] = s;
    __syncthreads();
    if (threadIdx.x == 0) stats[i] = p4[0] + p4[1] + p4[2] + p4[3];
}

// ---------------------------------------------------------------------------
// BN apply + ReLU from bf16 pre-out.
// ---------------------------------------------------------------------------
__global__ __launch_bounds__(256)
void bn_relu_kernel(const u16* __restrict__ pre16, const float* __restrict__ stats,
                    const float* __restrict__ gamma, const float* __restrict__ beta,
                    float* __restrict__ out) {
    int i4 = blockIdx.x * 256 + threadIdx.x;   // 4-element group index
    int ch = (i4 >> 12) & (O_ - 1);
    float mean = stats[ch] * (1.f / NPIX_);
    float var  = stats[64 + ch] * (1.f / NPIX_) - mean * mean;
    float scale = gamma[ch] * rsqrtf(var + BN_EPS_);
    float shift = beta[ch] - mean * scale;
    uint2 v = ((const uint2*)pre16)[i4];
    float4 o;
    o.x = fmaxf(fmaf(bf2f((u16)(v.x & 0xffff)), scale, shift), 0.f);
    o.y = fmaxf(fmaf(bf2f((u16)(v.x >> 16)),    scale, shift), 0.f);
    o.z = fmaxf(fmaf(bf2f((u16)(v.y & 0xffff)), scale, shift), 0.f);
    o.w = fmaxf(fmaf(bf2f((u16)(v.y >> 16)),    scale, shift), 0.f);
    ((float4*)out)[i4] = o;
}

// ---------------------------------------------------------------------------
extern "C" void kernel_launch(void* const* d_in, const int* in_sizes, int n_in,
                              void* d_out, int out_size, void* d_ws, size_t ws_size,
                              hipStream_t stream) {
    const float* x      = (const float*)d_in[0];
    const float* conv_w = (const float*)d_in[1];
    const float* off_w  = (const float*)d_in[2];
    const float* off_b  = (const float*)d_in[3];
    const float* mask_w = (const float*)d_in[4];
    const float* mask_b = (const float*)d_in[5];
    const float* gamma  = (const float*)d_in[6];
    const float* beta   = (const float*)d_in[7];
    float* out = (float*)d_out;

    // workspace layout: 11,317,760 B total (< 11,928,064 B proven safe in R1)
    char* ws = (char*)d_ws;
    u16*  xb16   = (u16*)(ws);                   // [2][64][16384] bf16 = 4,194,304
    u16*  off16  = (u16*)(ws + 4194304);         // [2][18][16384] f16  = 1,179,648
    u16*  mask16 = (u16*)(ws + 5373952);         // [2][9][16384] f16   =   589,824
    u16*  pre16  = (u16*)(ws + 5963776);         // [2][64][16384] bf16 = 4,194,304
    u16*  WpF    = (u16*)(ws + 10158080);        // 36,864 el           =    73,728
    u16*  W27F   = (u16*)(ws + 10231808);        // 18,432 el           =    36,864
    float* part  = (float*)(ws + 10268672);      // 2 x [2048][64] f32  = 1,048,576
    float* stats = (float*)(ws + 11317248);      // 128 f32 + pad       =       512

    prep_kernel<<<1240, 256, 0, stream>>>(x, conv_w, off_w, mask_w, xb16, WpF, W27F);
    gemm_a_kernel<<<NPIX_ / 32, 384, 0, stream>>>(xb16, W27F, off_b, mask_b, off16, mask16);
    gemm_b_kernel<<<NPIX_ / 32, 384, 0, stream>>>(xb16, off16, mask16, WpF, pre16, part);
    stats_red_kernel<<<128, 256, 0, stream>>>(part, stats);
    bn_relu_kernel<<<2048, 256, 0, stream>>>(pre16, stats, gamma, beta, out);
}

// Round 5
// 125.736 us; speedup vs baseline: 3.5430x; 1.1790x over previous
//
#include <hip/hip_runtime.h>
#include <hip/hip_fp16.h>

typedef __attribute__((ext_vector_type(8))) short bf16x8;
typedef __attribute__((ext_vector_type(4))) float f32x4;
typedef unsigned int  u32;
typedef unsigned short u16;

constexpr int B_  = 2;
constexpr int C_  = 64;
constexpr int O_  = 64;
constexpr int H_  = 128;
constexpr int W_  = 128;
constexpr int HW_ = H_ * W_;          // 16384
constexpr int NPIX_ = B_ * HW_;       // 32768
constexpr float BN_EPS_ = 1e-5f;

__device__ __forceinline__ u16 f2bf(float f) {
    u32 u = __float_as_uint(f);
    u = (u + 0x7fffu + ((u >> 16) & 1u)) >> 16;   // RNE
    return (u16)u;
}
__device__ __forceinline__ float bf2f(u16 v) { return __uint_as_float(((u32)v) << 16); }
__device__ __forceinline__ float bflo(u32 u) { return __uint_as_float(u << 16); }
__device__ __forceinline__ float bfhi(u32 u) { return __uint_as_float(u & 0xffff0000u); }
__device__ __forceinline__ u16 f2h(float f) { return __half_as_ushort(__float2half(f)); }
__device__ __forceinline__ float h2f(u16 v) { return __half2float(__ushort_as_half(v)); }

// ---------------------------------------------------------------------------
// prep: (1) transpose x -> xt[b][hw][c] bf16 (channel-contiguous per pixel),
//       (2) fragment-linear bf16 weights WpF / W27F (kk = tap*64 + c),
//       (3) zero the 128B zero-pad slot at xt[NPIX_*64].
// ---------------------------------------------------------------------------
__global__ __launch_bounds__(256)
void prep_kernel(const float* __restrict__ x, const float* __restrict__ conv_w,
                 const float* __restrict__ off_w, const float* __restrict__ mask_w,
                 u16* __restrict__ xt, u16* __restrict__ WpF, u16* __restrict__ W27F) {
    int bid = blockIdx.x, tid = threadIdx.x;
    if (bid < 512) {                        // x transpose: 64-pixel strip per block
        __shared__ u16 tile[64][66];
        int b = bid >> 8;
        int hw0 = (bid & 255) * 64;
        int c = tid >> 2, pq = (tid & 3) * 16;
        const float* src = x + (((size_t)(b * 64 + c)) << 14) + hw0 + pq;
#pragma unroll
        for (int i = 0; i < 4; i++) {
            float4 v = *(const float4*)(src + i * 4);
            tile[pq + i * 4 + 0][c] = f2bf(v.x);
            tile[pq + i * 4 + 1][c] = f2bf(v.y);
            tile[pq + i * 4 + 2][c] = f2bf(v.z);
            tile[pq + i * 4 + 3][c] = f2bf(v.w);
        }
        __syncthreads();
        int p = tid >> 2, cs = (tid & 3) * 16;
        uint4* dst = (uint4*)(xt + (((size_t)(b << 14)) + hw0 + p) * 64 + cs);
        dst[0] = *(const uint4*)&tile[p][cs];
        dst[1] = *(const uint4*)&tile[p][cs + 8];
    } else if (bid < 512 + 144) {           // WpF: 36,864 elements
        int i = (bid - 512) * 256 + tid;
        int j = i & 7, lane = (i >> 3) & 63, t = (i >> 9) & 3, s = i >> 11;
        int o = t * 16 + (lane & 15);
        int kk = s * 32 + (lane >> 4) * 8 + j;
        int tap = kk >> 6, c = kk & 63;
        WpF[i] = f2bf(conv_w[(o * 64 + c) * 9 + tap]);
    } else if (bid < 512 + 144 + 72) {      // W27F: 18,432 elements
        int i = (bid - 656) * 256 + tid;
        int j = i & 7, lane = (i >> 3) & 63, t = (i >> 9) & 1, s = i >> 10;
        int row = t * 16 + (lane & 15);
        int kk = s * 32 + (lane >> 4) * 8 + j;
        int tap = kk >> 6, c = kk & 63;
        float v = 0.f;
        if (row < 18) v = off_w[(row * 64 + c) * 9 + tap];
        else if (row < 27) v = mask_w[((row - 18) * 64 + c) * 9 + tap];
        W27F[i] = f2bf(v);
    } else {                                // zero-pad slot (for invalid im2col taps)
        if (tid < 64) xt[((u32)NPIX_ << 6) + tid] = 0;
    }
}

// ---------------------------------------------------------------------------
// GEMM-a (fused im2col), barrier-free K-loop. Block 384 thr = 6 waves =
// (2 px-groups of 16) x (3 K-thirds of 6 steps). Lane (quad,r): px = r-col,
// c = quad*8+j — one dwordx4 load from xt IS the B-fragment half.
// Invalid taps read the zeroed pad slot at xt[NPIX_*64].
// ---------------------------------------------------------------------------
template<int TAP>
__device__ __forceinline__ void metaA(int h, int w, u32 bb, u32 qoff, u32& abase) {
    constexpr int dh = TAP / 3 - 1, dw = TAP % 3 - 1;
    int hh = h + dh, ww = w + dw;
    bool valid = (hh >= 0) && (hh < H_) && (ww >= 0) && (ww < W_);
    u32 idx = valid ? (bb + (u32)(hh * W_ + ww)) : (u32)NPIX_;
    abase = (idx << 6) + qoff;
}

template<int SG>
__device__ __forceinline__ void stepA(const u16* __restrict__ xt,
                                      const u16* __restrict__ W27F, int lane,
                                      u32 abase, f32x4 (&acc)[2]) {
    constexpr u32 sc = (u32)(SG & 1) * 32u;
    bf16x8 sv = *(const bf16x8*)(xt + abase + sc);
#pragma unroll
    for (int t = 0; t < 2; t++) {
        bf16x8 af = *(const bf16x8*)(W27F + (u32)((SG * 2 + t) * 64 + lane) * 8u);
        acc[t] = __builtin_amdgcn_mfma_f32_16x16x32_bf16(af, sv, acc[t], 0, 0, 0);
    }
}

template<int KH>
__device__ __forceinline__ void runA(const u16* __restrict__ xt,
                                     const u16* __restrict__ W27F,
                                     int h, int w, u32 bb, u32 qoff, int lane,
                                     f32x4 (&acc)[2]) {
    u32 ab;
    metaA<3 * KH + 0>(h, w, bb, qoff, ab);
    stepA<6 * KH + 0>(xt, W27F, lane, ab, acc);
    stepA<6 * KH + 1>(xt, W27F, lane, ab, acc);
    metaA<3 * KH + 1>(h, w, bb, qoff, ab);
    stepA<6 * KH + 2>(xt, W27F, lane, ab, acc);
    stepA<6 * KH + 3>(xt, W27F, lane, ab, acc);
    metaA<3 * KH + 2>(h, w, bb, qoff, ab);
    stepA<6 * KH + 4>(xt, W27F, lane, ab, acc);
    stepA<6 * KH + 5>(xt, W27F, lane, ab, acc);
}

__global__ __launch_bounds__(384, 4)
void gemm_a_kernel(const u16* __restrict__ xt, const u16* __restrict__ W27F,
                   const float* __restrict__ off_b, const float* __restrict__ mask_b,
                   u16* __restrict__ off16, u16* __restrict__ mask16) {
    __shared__ float red[4][64][9];
    const int tid = threadIdx.x;
    const int lane = tid & 63, wv = tid >> 6;
    const int ph = wv & 1, kh = wv >> 1;
    const int quad = lane >> 4, r = lane & 15;
    const int pbase = blockIdx.x * 32;
    const int b = pbase >> 14, hwb = pbase & (HW_ - 1);
    const int hw = hwb + ph * 16 + r, h = hw >> 7, w = hw & (W_ - 1);
    const u32 bb = (u32)b << 14;
    const u32 qoff = (u32)quad * 8u;

    f32x4 acc[2];
    acc[0] = (f32x4){0.f, 0.f, 0.f, 0.f};
    acc[1] = (f32x4){0.f, 0.f, 0.f, 0.f};

    if (kh == 0)      runA<0>(xt, W27F, h, w, bb, qoff, lane, acc);
    else if (kh == 1) runA<1>(xt, W27F, h, w, bb, qoff, lane, acc);
    else              runA<2>(xt, W27F, h, w, bb, qoff, lane, acc);

    if (kh != 0) {
        int slot = (kh - 1) * 2 + ph;
#pragma unroll
        for (int t = 0; t < 2; t++)
#pragma unroll
            for (int g = 0; g < 4; g++) red[slot][lane][t * 4 + g] = acc[t][g];
    }
    __syncthreads();
    if (kh == 0) {
#pragma unroll
        for (int t = 0; t < 2; t++) {
#pragma unroll
            for (int g = 0; g < 4; g++) {
                float v = acc[t][g] + red[ph][lane][t * 4 + g] + red[2 + ph][lane][t * 4 + g];
                int o = t * 16 + quad * 4 + g;
                if (o < 18) {
                    v += off_b[o];
                    off16[(u32)(b * 18 + o) * HW_ + hw] = f2h(v);
                } else if (o < 27) {
                    v += mask_b[o - 18];
                    v = 1.f / (1.f + __expf(-v));
                    mask16[(u32)(b * 9 + (o - 18)) * HW_ + hw] = f2h(v);
                }
            }
        }
    }
}

// ---------------------------------------------------------------------------
// GEMM-b (fused bilinear sampler), barrier-free K-loop. Per step: 4 dwordx4
// corner loads (8 contiguous channels each) + fp32 bilinear combine -> B-frag.
// ---------------------------------------------------------------------------
template<int TAP>
__device__ __forceinline__ void metaB(const u16* __restrict__ off16,
                                      const u16* __restrict__ mask16,
                                      int b, int hw, int h, int w, u32 bb, u32 qoff,
                                      u32 (&qc)[4], float (&cw)[4]) {
    float dy = h2f(off16[(u32)(b * 18 + 2 * TAP) * HW_ + hw]);
    float dx = h2f(off16[(u32)(b * 18 + 2 * TAP + 1) * HW_ + hw]);
    float m  = h2f(mask16[(u32)(b * 9 + TAP) * HW_ + hw]);
    constexpr float kdy = (float)(TAP / 3 - 1), kdx = (float)(TAP % 3 - 1);
    float py = dy + (float)h + kdy;
    float px = dx + (float)w + kdx;
    float y0 = floorf(py), x0 = floorf(px);
    float ly = py - y0, lx = px - x0, hy = 1.f - ly, hx = 1.f - lx;
    float y1 = y0 + 1.f, x1 = x0 + 1.f;
    bool vy0 = (y0 >= 0.f) && (y0 <= 127.f);
    bool vy1 = (y1 >= 0.f) && (y1 <= 127.f);
    bool vx0 = (x0 >= 0.f) && (x0 <= 127.f);
    bool vx1 = (x1 >= 0.f) && (x1 <= 127.f);
    int iy0 = (int)fminf(fmaxf(y0, 0.f), 127.f);
    int iy1 = (int)fminf(fmaxf(y1, 0.f), 127.f);
    int ix0 = (int)fminf(fmaxf(x0, 0.f), 127.f);
    int ix1 = (int)fminf(fmaxf(x1, 0.f), 127.f);
    qc[0] = ((bb + (u32)(iy0 * W_ + ix0)) << 6) + qoff; cw[0] = (vy0 && vx0) ? hy * hx * m : 0.f;
    qc[1] = ((bb + (u32)(iy0 * W_ + ix1)) << 6) + qoff; cw[1] = (vy0 && vx1) ? hy * lx * m : 0.f;
    qc[2] = ((bb + (u32)(iy1 * W_ + ix0)) << 6) + qoff; cw[2] = (vy1 && vx0) ? ly * hx * m : 0.f;
    qc[3] = ((bb + (u32)(iy1 * W_ + ix1)) << 6) + qoff; cw[3] = (vy1 && vx1) ? ly * lx * m : 0.f;
}

template<int SG>
__device__ __forceinline__ void stepB(const u16* __restrict__ xt,
                                      const u16* __restrict__ WpF, int lane,
                                      const u32 (&qc)[4], const float (&cw)[4],
                                      f32x4 (&acc)[4]) {
    constexpr u32 sc = (u32)(SG & 1) * 32u;
    uint4 c0 = *(const uint4*)(xt + qc[0] + sc);
    uint4 c1 = *(const uint4*)(xt + qc[1] + sc);
    uint4 c2 = *(const uint4*)(xt + qc[2] + sc);
    uint4 c3 = *(const uint4*)(xt + qc[3] + sc);
    const u32* p0 = &c0.x; const u32* p1 = &c1.x;
    const u32* p2 = &c2.x; const u32* p3 = &c3.x;
    bf16x8 sv;
#pragma unroll
    for (int i = 0; i < 4; i++) {
        float lo = cw[0] * bflo(p0[i]) + cw[1] * bflo(p1[i])
                 + cw[2] * bflo(p2[i]) + cw[3] * bflo(p3[i]);
        float hi = cw[0] * bfhi(p0[i]) + cw[1] * bfhi(p1[i])
                 + cw[2] * bfhi(p2[i]) + cw[3] * bfhi(p3[i]);
        sv[2 * i]     = (short)f2bf(lo);
        sv[2 * i + 1] = (short)f2bf(hi);
    }
#pragma unroll
    for (int t = 0; t < 4; t++) {
        bf16x8 af = *(const bf16x8*)(WpF + (u32)((SG * 4 + t) * 64 + lane) * 8u);
        acc[t] = __builtin_amdgcn_mfma_f32_16x16x32_bf16(af, sv, acc[t], 0, 0, 0);
    }
}

template<int KH>
__device__ __forceinline__ void runB(const u16* __restrict__ xt,
                                     const u16* __restrict__ off16,
                                     const u16* __restrict__ mask16,
                                     const u16* __restrict__ WpF,
                                     int b, int hw, int h, int w, u32 bb, u32 qoff,
                                     int lane, f32x4 (&acc)[4]) {
    u32 qc[4]; float cw[4];
    metaB<3 * KH + 0>(off16, mask16, b, hw, h, w, bb, qoff, qc, cw);
    stepB<6 * KH + 0>(xt, WpF, lane, qc, cw, acc);
    stepB<6 * KH + 1>(xt, WpF, lane, qc, cw, acc);
    metaB<3 * KH + 1>(off16, mask16, b, hw, h, w, bb, qoff, qc, cw);
    stepB<6 * KH + 2>(xt, WpF, lane, qc, cw, acc);
    stepB<6 * KH + 3>(xt, WpF, lane, qc, cw, acc);
    metaB<3 * KH + 2>(off16, mask16, b, hw, h, w, bb, qoff, qc, cw);
    stepB<6 * KH + 4>(xt, WpF, lane, qc, cw, acc);
    stepB<6 * KH + 5>(xt, WpF, lane, qc, cw, acc);
}

__global__ __launch_bounds__(384, 4)
void gemm_b_kernel(const u16* __restrict__ xt, const u16* __restrict__ off16,
                   const u16* __restrict__ mask16, const u16* __restrict__ WpF,
                   u16* __restrict__ pre16, float* __restrict__ part) {
    __shared__ float red[4][64][17];
    const int tid = threadIdx.x;
    const int lane = tid & 63, wv = tid >> 6;
    const int ph = wv & 1, kh = wv >> 1;
    const int quad = lane >> 4, r = lane & 15;
    const int pbase = blockIdx.x * 32;
    const int b = pbase >> 14, hwb = pbase & (HW_ - 1);
    const int hw = hwb + ph * 16 + r, h = hw >> 7, w = hw & (W_ - 1);
    const u32 bb = (u32)b << 14;
    const u32 qoff = (u32)quad * 8u;

    f32x4 acc[4];
#pragma unroll
    for (int t = 0; t < 4; t++) acc[t] = (f32x4){0.f, 0.f, 0.f, 0.f};

    if (kh == 0)      runB<0>(xt, off16, mask16, WpF, b, hw, h, w, bb, qoff, lane, acc);
    else if (kh == 1) runB<1>(xt, off16, mask16, WpF, b, hw, h, w, bb, qoff, lane, acc);
    else              runB<2>(xt, off16, mask16, WpF, b, hw, h, w, bb, qoff, lane, acc);

    if (kh != 0) {
        int slot = (kh - 1) * 2 + ph;
#pragma unroll
        for (int t = 0; t < 4; t++)
#pragma unroll
            for (int g = 0; g < 4; g++) red[slot][lane][t * 4 + g] = acc[t][g];
    }
    __syncthreads();
    if (kh == 0) {
        const u32 slot = (u32)blockIdx.x * 2 + (u32)ph;
#pragma unroll
        for (int t = 0; t < 4; t++) {
#pragma unroll
            for (int g = 0; g < 4; g++) {
                float v = acc[t][g] + red[ph][lane][t * 4 + g] + red[2 + ph][lane][t * 4 + g];
                int o = t * 16 + quad * 4 + g;
                pre16[(u32)(b * 64 + o) * HW_ + hw] = f2bf(v);
                float s = v, s2 = v * v;
#pragma unroll
                for (int off = 8; off >= 1; off >>= 1) {
                    s  += __shfl_down(s, off, 16);
                    s2 += __shfl_down(s2, off, 16);
                }
                if (r == 0) {
                    part[(u32)o * 2048 + slot] = s;            // sums
                    part[131072 + (u32)o * 2048 + slot] = s2;  // sumsqs
                }
            }
        }
    }
}

// ---------------------------------------------------------------------------
// stats reduce: stats[i] (i<64 sum, i>=64 sumsq) = Σ over 2048 contiguous
// block-partials (coalesced).
// ---------------------------------------------------------------------------
__global__ __launch_bounds__(256)
void stats_red_kernel(const float* __restrict__ part, float* __restrict__ stats) {
    __shared__ float p4[4];
    int i = blockIdx.x;                       // 0..127
    const float* src = part + (u32)(i >> 6) * 131072 + (u32)(i & 63) * 2048;
    float s = 0.f;
    for (int rr = threadIdx.x; rr < 2048; rr += 256) s += src[rr];
#pragma unroll
    for (int off = 32; off >= 1; off >>= 1) s += __shfl_down(s, off);
    if ((threadIdx.x & 63) == 0) p4[threadIdx.x >> 6] = s;
    __syncthreads();
    if (threadIdx.x == 0) stats[i] = p4[0] + p4[1] + p4[2] + p4[3];
}

// ---------------------------------------------------------------------------
// BN apply + ReLU from bf16 pre-out.
// ---------------------------------------------------------------------------
__global__ __launch_bounds__(256)
void bn_relu_kernel(const u16* __restrict__ pre16, const float* __restrict__ stats,
                    const float* __restrict__ gamma, const float* __restrict__ beta,
                    float* __restrict__ out) {
    int i4 = blockIdx.x * 256 + threadIdx.x;   // 4-element group index
    int ch = (i4 >> 12) & (O_ - 1);
    float mean = stats[ch] * (1.f / NPIX_);
    float var  = stats[64 + ch] * (1.f / NPIX_) - mean * mean;
    float scale = gamma[ch] * rsqrtf(var + BN_EPS_);
    float shift = beta[ch] - mean * scale;
    uint2 v = ((const uint2*)pre16)[i4];
    float4 o;
    o.x = fmaxf(fmaf(bflo(v.x), scale, shift), 0.f);
    o.y = fmaxf(fmaf(bfhi(v.x), scale, shift), 0.f);
    o.z = fmaxf(fmaf(bflo(v.y), scale, shift), 0.f);
    o.w = fmaxf(fmaf(bfhi(v.y), scale, shift), 0.f);
    ((float4*)out)[i4] = o;
}

// ---------------------------------------------------------------------------
extern "C" void kernel_launch(void* const* d_in, const int* in_sizes, int n_in,
                              void* d_out, int out_size, void* d_ws, size_t ws_size,
                              hipStream_t stream) {
    const float* x      = (const float*)d_in[0];
    const float* conv_w = (const float*)d_in[1];
    const float* off_w  = (const float*)d_in[2];
    const float* off_b  = (const float*)d_in[3];
    const float* mask_w = (const float*)d_in[4];
    const float* mask_b = (const float*)d_in[5];
    const float* gamma  = (const float*)d_in[6];
    const float* beta   = (const float*)d_in[7];
    float* out = (float*)d_out;

    // workspace layout: 11,317,888 B total (< 11,928,064 B proven safe in R1)
    char* ws = (char*)d_ws;
    u16*  xt     = (u16*)(ws);                   // [2][16384][64] bf16 + 128B pad = 4,194,432
    u16*  off16  = (u16*)(ws + 4194432);         // [2][18][16384] f16  = 1,179,648
    u16*  mask16 = (u16*)(ws + 5374080);         // [2][9][16384] f16   =   589,824
    u16*  pre16  = (u16*)(ws + 5963904);         // [2][64][16384] bf16 = 4,194,304
    u16*  WpF    = (u16*)(ws + 10158208);        // 36,864 el           =    73,728
    u16*  W27F   = (u16*)(ws + 10231936);        // 18,432 el           =    36,864
    float* part  = (float*)(ws + 10268800);      // 2 x [64][2048] f32  = 1,048,576
    float* stats = (float*)(ws + 11317376);      // 128 f32 + pad       =       512

    prep_kernel<<<729, 256, 0, stream>>>(x, conv_w, off_w, mask_w, xt, WpF, W27F);
    gemm_a_kernel<<<NPIX_ / 32, 384, 0, stream>>>(xt, W27F, off_b, mask_b, off16, mask16);
    gemm_b_kernel<<<NPIX_ / 32, 384, 0, stream>>>(xt, off16, mask16, WpF, pre16, part);
    stats_red_kernel<<<128, 256, 0, stream>>>(part, stats);
    bn_relu_kernel<<<2048, 256, 0, stream>>>(pre16, stats, gamma, beta, out);
}

// Round 6
// 123.705 us; speedup vs baseline: 3.6012x; 1.0164x over previous
//
#include <hip/hip_runtime.h>

typedef __attribute__((ext_vector_type(8))) short bf16x8;
typedef __attribute__((ext_vector_type(4))) float f32x4;
typedef unsigned int  u32;
typedef unsigned short u16;

constexpr int B_  = 2;
constexpr int C_  = 64;
constexpr int O_  = 64;
constexpr int H_  = 128;
constexpr int W_  = 128;
constexpr int HW_ = H_ * W_;          // 16384
constexpr int NPIX_ = B_ * HW_;       // 32768
constexpr float BN_EPS_ = 1e-5f;

__device__ __forceinline__ u16 f2bf(float f) {
    u32 u = __float_as_uint(f);
    u = (u + 0x7fffu + ((u >> 16) & 1u)) >> 16;   // RNE
    return (u16)u;
}
__device__ __forceinline__ float bflo(u32 u) { return __uint_as_float(u << 16); }
__device__ __forceinline__ float bfhi(u32 u) { return __uint_as_float(u & 0xffff0000u); }

// ---------------------------------------------------------------------------
// prep: (1) transpose x -> xt[b][hw][c] bf16 (channel-contiguous per pixel),
//       (2) fragment-linear bf16 weights WpF / W27F (kk = tap*64 + c),
//       (3) zero the 128B pad slot at xt[NPIX_*64] (target of invalid taps).
// ---------------------------------------------------------------------------
__global__ __launch_bounds__(256)
void prep_kernel(const float* __restrict__ x, const float* __restrict__ conv_w,
                 const float* __restrict__ off_w, const float* __restrict__ mask_w,
                 u16* __restrict__ xt, u16* __restrict__ WpF, u16* __restrict__ W27F) {
    int bid = blockIdx.x, tid = threadIdx.x;
    if (bid < 512) {                        // x transpose: 64-pixel strip per block
        __shared__ u16 tile[64][66];
        int b = bid >> 8;
        int hw0 = (bid & 255) * 64;
        int c = tid >> 2, pq = (tid & 3) * 16;
        const float* src = x + (((size_t)(b * 64 + c)) << 14) + hw0 + pq;
#pragma unroll
        for (int i = 0; i < 4; i++) {
            float4 v = *(const float4*)(src + i * 4);
            tile[pq + i * 4 + 0][c] = f2bf(v.x);
            tile[pq + i * 4 + 1][c] = f2bf(v.y);
            tile[pq + i * 4 + 2][c] = f2bf(v.z);
            tile[pq + i * 4 + 3][c] = f2bf(v.w);
        }
        __syncthreads();
        int p = tid >> 2, cs = (tid & 3) * 16;
        uint4* dst = (uint4*)(xt + (((size_t)(b << 14)) + hw0 + p) * 64 + cs);
        dst[0] = *(const uint4*)&tile[p][cs];
        dst[1] = *(const uint4*)&tile[p][cs + 8];
    } else if (bid < 512 + 144) {           // WpF: 36,864 elements
        int i = (bid - 512) * 256 + tid;
        int j = i & 7, lane = (i >> 3) & 63, t = (i >> 9) & 3, s = i >> 11;
        int o = t * 16 + (lane & 15);
        int kk = s * 32 + (lane >> 4) * 8 + j;
        int tap = kk >> 6, c = kk & 63;
        WpF[i] = f2bf(conv_w[(o * 64 + c) * 9 + tap]);
    } else if (bid < 512 + 144 + 72) {      // W27F: 18,432 elements
        int i = (bid - 656) * 256 + tid;
        int j = i & 7, lane = (i >> 3) & 63, t = (i >> 9) & 1, s = i >> 10;
        int row = t * 16 + (lane & 15);
        int kk = s * 32 + (lane >> 4) * 8 + j;
        int tap = kk >> 6, c = kk & 63;
        float v = 0.f;
        if (row < 18) v = off_w[(row * 64 + c) * 9 + tap];
        else if (row < 27) v = mask_w[((row - 18) * 64 + c) * 9 + tap];
        W27F[i] = f2bf(v);
    } else {                                // zero-pad slot (invalid im2col taps)
        if (tid < 64) xt[((u32)NPIX_ << 6) + tid] = 0;
    }
}

// ---------------------------------------------------------------------------
// Phase A helpers (im2col GEMM for 27 offset/mask rows). Lane (quad,r):
// px = r, c = quad*8+j — one dwordx4 load from xt IS the B-fragment half.
// ---------------------------------------------------------------------------
template<int TAP>
__device__ __forceinline__ void metaA(int h, int w, u32 bb, u32 qoff, u32& abase) {
    constexpr int dh = TAP / 3 - 1, dw = TAP % 3 - 1;
    int hh = h + dh, ww = w + dw;
    bool valid = (hh >= 0) && (hh < H_) && (ww >= 0) && (ww < W_);
    u32 idx = valid ? (bb + (u32)(hh * W_ + ww)) : (u32)NPIX_;
    abase = (idx << 6) + qoff;
}

template<int SG>
__device__ __forceinline__ void stepA(const u16* __restrict__ xt,
                                      const u16* __restrict__ W27F, int lane,
                                      u32 abase, f32x4 (&acc)[2]) {
    constexpr u32 sc = (u32)(SG & 1) * 32u;
    bf16x8 sv = *(const bf16x8*)(xt + abase + sc);
#pragma unroll
    for (int t = 0; t < 2; t++) {
        bf16x8 af = *(const bf16x8*)(W27F + (u32)((SG * 2 + t) * 64 + lane) * 8u);
        acc[t] = __builtin_amdgcn_mfma_f32_16x16x32_bf16(af, sv, acc[t], 0, 0, 0);
    }
}

template<int KH>
__device__ __forceinline__ void runA(const u16* __restrict__ xt,
                                     const u16* __restrict__ W27F,
                                     int h, int w, u32 bb, u32 qoff, int lane,
                                     f32x4 (&acc)[2]) {
    u32 ab;
    metaA<3 * KH + 0>(h, w, bb, qoff, ab);
    stepA<6 * KH + 0>(xt, W27F, lane, ab, acc);
    stepA<6 * KH + 1>(xt, W27F, lane, ab, acc);
    metaA<3 * KH + 1>(h, w, bb, qoff, ab);
    stepA<6 * KH + 2>(xt, W27F, lane, ab, acc);
    stepA<6 * KH + 3>(xt, W27F, lane, ab, acc);
    metaA<3 * KH + 2>(h, w, bb, qoff, ab);
    stepA<6 * KH + 4>(xt, W27F, lane, ab, acc);
    stepA<6 * KH + 5>(xt, W27F, lane, ab, acc);
}

// ---------------------------------------------------------------------------
// Phase B helpers (bilinear sampler GEMM). Meta comes from LDS (fp32).
// ---------------------------------------------------------------------------
template<int TAP>
__device__ __forceinline__ void metaB(const float* __restrict__ moff,
                                      const float* __restrict__ mmask,
                                      int p32, int h, int w, u32 bb, u32 qoff,
                                      u32 (&qc)[4], float (&cw)[4]) {
    float dy = moff[(2 * TAP) * 32 + p32];
    float dx = moff[(2 * TAP + 1) * 32 + p32];
    float m  = mmask[TAP * 32 + p32];
    constexpr float kdy = (float)(TAP / 3 - 1), kdx = (float)(TAP % 3 - 1);
    float py = dy + (float)h + kdy;
    float px = dx + (float)w + kdx;
    float y0 = floorf(py), x0 = floorf(px);
    float ly = py - y0, lx = px - x0, hy = 1.f - ly, hx = 1.f - lx;
    float y1 = y0 + 1.f, x1 = x0 + 1.f;
    bool vy0 = (y0 >= 0.f) && (y0 <= 127.f);
    bool vy1 = (y1 >= 0.f) && (y1 <= 127.f);
    bool vx0 = (x0 >= 0.f) && (x0 <= 127.f);
    bool vx1 = (x1 >= 0.f) && (x1 <= 127.f);
    int iy0 = (int)fminf(fmaxf(y0, 0.f), 127.f);
    int iy1 = (int)fminf(fmaxf(y1, 0.f), 127.f);
    int ix0 = (int)fminf(fmaxf(x0, 0.f), 127.f);
    int ix1 = (int)fminf(fmaxf(x1, 0.f), 127.f);
    qc[0] = ((bb + (u32)(iy0 * W_ + ix0)) << 6) + qoff; cw[0] = (vy0 && vx0) ? hy * hx * m : 0.f;
    qc[1] = ((bb + (u32)(iy0 * W_ + ix1)) << 6) + qoff; cw[1] = (vy0 && vx1) ? hy * lx * m : 0.f;
    qc[2] = ((bb + (u32)(iy1 * W_ + ix0)) << 6) + qoff; cw[2] = (vy1 && vx0) ? ly * hx * m : 0.f;
    qc[3] = ((bb + (u32)(iy1 * W_ + ix1)) << 6) + qoff; cw[3] = (vy1 && vx1) ? ly * lx * m : 0.f;
}

template<int SG>
__device__ __forceinline__ void stepB(const u16* __restrict__ xt,
                                      const u16* __restrict__ WpF, int lane,
                                      const u32 (&qc)[4], const float (&cw)[4],
                                      f32x4 (&acc)[4]) {
    constexpr u32 sc = (u32)(SG & 1) * 32u;
    uint4 c0 = *(const uint4*)(xt + qc[0] + sc);
    uint4 c1 = *(const uint4*)(xt + qc[1] + sc);
    uint4 c2 = *(const uint4*)(xt + qc[2] + sc);
    uint4 c3 = *(const uint4*)(xt + qc[3] + sc);
    const u32* p0 = &c0.x; const u32* p1 = &c1.x;
    const u32* p2 = &c2.x; const u32* p3 = &c3.x;
    bf16x8 sv;
#pragma unroll
    for (int i = 0; i < 4; i++) {
        float lo = cw[0] * bflo(p0[i]) + cw[1] * bflo(p1[i])
                 + cw[2] * bflo(p2[i]) + cw[3] * bflo(p3[i]);
        float hi = cw[0] * bfhi(p0[i]) + cw[1] * bfhi(p1[i])
                 + cw[2] * bfhi(p2[i]) + cw[3] * bfhi(p3[i]);
        sv[2 * i]     = (short)f2bf(lo);
        sv[2 * i + 1] = (short)f2bf(hi);
    }
#pragma unroll
    for (int t = 0; t < 4; t++) {
        bf16x8 af = *(const bf16x8*)(WpF + (u32)((SG * 4 + t) * 64 + lane) * 8u);
        acc[t] = __builtin_amdgcn_mfma_f32_16x16x32_bf16(af, sv, acc[t], 0, 0, 0);
    }
}

template<int KH>
__device__ __forceinline__ void runB(const u16* __restrict__ xt,
                                     const float* __restrict__ moff,
                                     const float* __restrict__ mmask,
                                     const u16* __restrict__ WpF,
                                     int p32, int h, int w, u32 bb, u32 qoff,
                                     int lane, f32x4 (&acc)[4]) {
    u32 qc[4]; float cw[4];
    metaB<3 * KH + 0>(moff, mmask, p32, h, w, bb, qoff, qc, cw);
    stepB<6 * KH + 0>(xt, WpF, lane, qc, cw, acc);
    stepB<6 * KH + 1>(xt, WpF, lane, qc, cw, acc);
    metaB<3 * KH + 1>(moff, mmask, p32, h, w, bb, qoff, qc, cw);
    stepB<6 * KH + 2>(xt, WpF, lane, qc, cw, acc);
    stepB<6 * KH + 3>(xt, WpF, lane, qc, cw, acc);
    metaB<3 * KH + 2>(moff, mmask, p32, h, w, bb, qoff, qc, cw);
    stepB<6 * KH + 4>(xt, WpF, lane, qc, cw, acc);
    stepB<6 * KH + 5>(xt, WpF, lane, qc, cw, acc);
}

// ---------------------------------------------------------------------------
// Fused GEMM-a + GEMM-b. Block = 32 pixels, 384 thr = 6 waves =
// (2 px-groups ph of 16) x (3 K-thirds kh). Phase A: offset/mask -> LDS fp32.
// Phase B: sampler GEMM with LDS meta. Epilogue: LDS reduce K-thirds, bf16
// pre-out, per-block stats partials.
// ---------------------------------------------------------------------------
__global__ __launch_bounds__(384, 4)
void gemm_ab_kernel(const u16* __restrict__ xt, const u16* __restrict__ W27F,
                    const u16* __restrict__ WpF,
                    const float* __restrict__ off_b, const float* __restrict__ mask_b,
                    u16* __restrict__ pre16, float* __restrict__ part) {
    __shared__ float red[4][64][17];
    __shared__ float moff[18 * 32];
    __shared__ float mmask[9 * 32];
    const int tid = threadIdx.x;
    const int lane = tid & 63, wv = tid >> 6;
    const int ph = wv & 1, kh = wv >> 1;
    const int quad = lane >> 4, r = lane & 15;
    const int pbase = blockIdx.x * 32;
    const int b = pbase >> 14, hwb = pbase & (HW_ - 1);
    const int p32 = ph * 16 + r;
    const int hw = hwb + p32, h = hw >> 7, w = hw & (W_ - 1);
    const u32 bb = (u32)b << 14;
    const u32 qoff = (u32)quad * 8u;

    // ---------------- Phase A: offsets + mask into LDS ----------------
    {
        f32x4 acc[2];
        acc[0] = (f32x4){0.f, 0.f, 0.f, 0.f};
        acc[1] = (f32x4){0.f, 0.f, 0.f, 0.f};
        if (kh == 0)      runA<0>(xt, W27F, h, w, bb, qoff, lane, acc);
        else if (kh == 1) runA<1>(xt, W27F, h, w, bb, qoff, lane, acc);
        else              runA<2>(xt, W27F, h, w, bb, qoff, lane, acc);

        if (kh != 0) {
            int slot = (kh - 1) * 2 + ph;
#pragma unroll
            for (int t = 0; t < 2; t++)
#pragma unroll
                for (int g = 0; g < 4; g++) red[slot][lane][t * 4 + g] = acc[t][g];
        }
        __syncthreads();
        if (kh == 0) {
#pragma unroll
            for (int t = 0; t < 2; t++) {
#pragma unroll
                for (int g = 0; g < 4; g++) {
                    float v = acc[t][g] + red[ph][lane][t * 4 + g] + red[2 + ph][lane][t * 4 + g];
                    int o = t * 16 + quad * 4 + g;
                    if (o < 18) {
                        moff[o * 32 + p32] = v + off_b[o];
                    } else if (o < 27) {
                        v += mask_b[o - 18];
                        mmask[(o - 18) * 32 + p32] = 1.f / (1.f + __expf(-v));
                    }
                }
            }
        }
        __syncthreads();
    }

    // ---------------- Phase B: sampler GEMM ----------------
    f32x4 acc[4];
#pragma unroll
    for (int t = 0; t < 4; t++) acc[t] = (f32x4){0.f, 0.f, 0.f, 0.f};

    if (kh == 0)      runB<0>(xt, moff, mmask, WpF, p32, h, w, bb, qoff, lane, acc);
    else if (kh == 1) runB<1>(xt, moff, mmask, WpF, p32, h, w, bb, qoff, lane, acc);
    else              runB<2>(xt, moff, mmask, WpF, p32, h, w, bb, qoff, lane, acc);

    if (kh != 0) {
        int slot = (kh - 1) * 2 + ph;
#pragma unroll
        for (int t = 0; t < 4; t++)
#pragma unroll
            for (int g = 0; g < 4; g++) red[slot][lane][t * 4 + g] = acc[t][g];
    }
    __syncthreads();
    if (kh == 0) {
        const u32 slot = (u32)blockIdx.x * 2 + (u32)ph;
#pragma unroll
        for (int t = 0; t < 4; t++) {
#pragma unroll
            for (int g = 0; g < 4; g++) {
                float v = acc[t][g] + red[ph][lane][t * 4 + g] + red[2 + ph][lane][t * 4 + g];
                int o = t * 16 + quad * 4 + g;
                pre16[(u32)(b * 64 + o) * HW_ + hw] = f2bf(v);
                float s = v, s2 = v * v;
#pragma unroll
                for (int off = 8; off >= 1; off >>= 1) {
                    s  += __shfl_down(s, off, 16);
                    s2 += __shfl_down(s2, off, 16);
                }
                if (r == 0) {
                    part[(u32)o * 2048 + slot] = s;            // sums
                    part[131072 + (u32)o * 2048 + slot] = s2;  // sumsqs
                }
            }
        }
    }
}

// ---------------------------------------------------------------------------
// stats reduce: stats[i] (i<64 sum, i>=64 sumsq) = Σ over 2048 contiguous
// block-partials (coalesced).
// ---------------------------------------------------------------------------
__global__ __launch_bounds__(256)
void stats_red_kernel(const float* __restrict__ part, float* __restrict__ stats) {
    __shared__ float p4[4];
    int i = blockIdx.x;                       // 0..127
    const float* src = part + (u32)(i >> 6) * 131072 + (u32)(i & 63) * 2048;
    float s = 0.f;
    for (int rr = threadIdx.x; rr < 2048; rr += 256) s += src[rr];
#pragma unroll
    for (int off = 32; off >= 1; off >>= 1) s += __shfl_down(s, off);
    if ((threadIdx.x & 63) == 0) p4[threadIdx.x >> 6] = s;
    __syncthreads();
    if (threadIdx.x == 0) stats[i] = p4[0] + p4[1] + p4[2] + p4[3];
}

// ---------------------------------------------------------------------------
// BN apply + ReLU from bf16 pre-out.
// ---------------------------------------------------------------------------
__global__ __launch_bounds__(256)
void bn_relu_kernel(const u16* __restrict__ pre16, const float* __restrict__ stats,
                    const float* __restrict__ gamma, const float* __restrict__ beta,
                    float* __restrict__ out) {
    int i4 = blockIdx.x * 256 + threadIdx.x;   // 4-element group index
    int ch = (i4 >> 12) & (O_ - 1);
    float mean = stats[ch] * (1.f / NPIX_);
    float var  = stats[64 + ch] * (1.f / NPIX_) - mean * mean;
    float scale = gamma[ch] * rsqrtf(var + BN_EPS_);
    float shift = beta[ch] - mean * scale;
    uint2 v = ((const uint2*)pre16)[i4];
    float4 o;
    o.x = fmaxf(fmaf(bflo(v.x), scale, shift), 0.f);
    o.y = fmaxf(fmaf(bfhi(v.x), scale, shift), 0.f);
    o.z = fmaxf(fmaf(bflo(v.y), scale, shift), 0.f);
    o.w = fmaxf(fmaf(bfhi(v.y), scale, shift), 0.f);
    ((float4*)out)[i4] = o;
}

// ---------------------------------------------------------------------------
extern "C" void kernel_launch(void* const* d_in, const int* in_sizes, int n_in,
                              void* d_out, int out_size, void* d_ws, size_t ws_size,
                              hipStream_t stream) {
    const float* x      = (const float*)d_in[0];
    const float* conv_w = (const float*)d_in[1];
    const float* off_w  = (const float*)d_in[2];
    const float* off_b  = (const float*)d_in[3];
    const float* mask_w = (const float*)d_in[4];
    const float* mask_b = (const float*)d_in[5];
    const float* gamma  = (const float*)d_in[6];
    const float* beta   = (const float*)d_in[7];
    float* out = (float*)d_out;

    // workspace layout: 9,548,416 B total (ws_size ~268 MB per R5 fill size)
    char* ws = (char*)d_ws;
    u16*  xt     = (u16*)(ws);                   // [2][16384][64] bf16 + 128B pad = 4,194,432
    u16*  pre16  = (u16*)(ws + 4194432);         // [2][64][16384] bf16 = 4,194,304
    u16*  WpF    = (u16*)(ws + 8388736);         // 36,864 el = 73,728
    u16*  W27F   = (u16*)(ws + 8462464);         // 18,432 el = 36,864
    float* part  = (float*)(ws + 8499328);       // 2 x [64][2048] f32 = 1,048,576
    float* stats = (float*)(ws + 9547904);       // 128 f32 = 512

    prep_kernel<<<729, 256, 0, stream>>>(x, conv_w, off_w, mask_w, xt, WpF, W27F);
    gemm_ab_kernel<<<NPIX_ / 32, 384, 0, stream>>>(xt, W27F, WpF, off_b, mask_b, pre16, part);
    stats_red_kernel<<<128, 256, 0, stream>>>(part, stats);
    bn_relu_kernel<<<2048, 256, 0, stream>>>(pre16, stats, gamma, beta, out);
}

// Round 7
// 122.714 us; speedup vs baseline: 3.6303x; 1.0081x over previous
//
#include <hip/hip_runtime.h>

typedef __attribute__((ext_vector_type(8))) short bf16x8;
typedef __attribute__((ext_vector_type(4))) float f32x4;
typedef unsigned int  u32;
typedef unsigned short u16;

constexpr int B_  = 2;
constexpr int C_  = 64;
constexpr int O_  = 64;
constexpr int H_  = 128;
constexpr int W_  = 128;
constexpr int HW_ = H_ * W_;          // 16384
constexpr int NPIX_ = B_ * HW_;       // 32768
constexpr float BN_EPS_ = 1e-5f;

__device__ __forceinline__ u16 f2bf(float f) {
    u32 u = __float_as_uint(f);
    u = (u + 0x7fffu + ((u >> 16) & 1u)) >> 16;   // RNE
    return (u16)u;
}
__device__ __forceinline__ float bflo(u32 u) { return __uint_as_float(u << 16); }
__device__ __forceinline__ float bfhi(u32 u) { return __uint_as_float(u & 0xffff0000u); }

// ---------------------------------------------------------------------------
// prep: (1) transpose x -> xt[b][hw][c] bf16 (channel-contiguous per pixel),
//       (2) fragment-linear bf16 weights WpF / W27F (kk = tap*64 + c),
//       (3) zero the 128B pad slot at xt[NPIX_*64] (target of invalid taps).
// ---------------------------------------------------------------------------
__global__ __launch_bounds__(256)
void prep_kernel(const float* __restrict__ x, const float* __restrict__ conv_w,
                 const float* __restrict__ off_w, const float* __restrict__ mask_w,
                 u16* __restrict__ xt, u16* __restrict__ WpF, u16* __restrict__ W27F) {
    int bid = blockIdx.x, tid = threadIdx.x;
    if (bid < 512) {                        // x transpose: 64-pixel strip per block
        __shared__ u16 tile[64][66];
        int b = bid >> 8;
        int hw0 = (bid & 255) * 64;
        int c = tid >> 2, pq = (tid & 3) * 16;
        const float* src = x + (((size_t)(b * 64 + c)) << 14) + hw0 + pq;
#pragma unroll
        for (int i = 0; i < 4; i++) {
            float4 v = *(const float4*)(src + i * 4);
            tile[pq + i * 4 + 0][c] = f2bf(v.x);
            tile[pq + i * 4 + 1][c] = f2bf(v.y);
            tile[pq + i * 4 + 2][c] = f2bf(v.z);
            tile[pq + i * 4 + 3][c] = f2bf(v.w);
        }
        __syncthreads();
        int p = tid >> 2, cs = (tid & 3) * 16;
        uint4* dst = (uint4*)(xt + (((size_t)(b << 14)) + hw0 + p) * 64 + cs);
        dst[0] = *(const uint4*)&tile[p][cs];
        dst[1] = *(const uint4*)&tile[p][cs + 8];
    } else if (bid < 512 + 144) {           // WpF: 36,864 elements
        int i = (bid - 512) * 256 + tid;
        int j = i & 7, lane = (i >> 3) & 63, t = (i >> 9) & 3, s = i >> 11;
        int o = t * 16 + (lane & 15);
        int kk = s * 32 + (lane >> 4) * 8 + j;
        int tap = kk >> 6, c = kk & 63;
        WpF[i] = f2bf(conv_w[(o * 64 + c) * 9 + tap]);
    } else if (bid < 512 + 144 + 72) {      // W27F: 18,432 elements
        int i = (bid - 656) * 256 + tid;
        int j = i & 7, lane = (i >> 3) & 63, t = (i >> 9) & 1, s = i >> 10;
        int row = t * 16 + (lane & 15);
        int kk = s * 32 + (lane >> 4) * 8 + j;
        int tap = kk >> 6, c = kk & 63;
        float v = 0.f;
        if (row < 18) v = off_w[(row * 64 + c) * 9 + tap];
        else if (row < 27) v = mask_w[((row - 18) * 64 + c) * 9 + tap];
        W27F[i] = f2bf(v);
    } else {                                // zero-pad slot (invalid im2col taps)
        if (tid < 64) xt[((u32)NPIX_ << 6) + tid] = 0;
    }
}

// ---------------------------------------------------------------------------
// Phase A helpers (im2col GEMM for 27 offset/mask rows). Lane (quad,r):
// px = r, c = quad*8+j — one dwordx4 load from xt IS the B-fragment half.
// All 6 fragment loads of a K-third are issued before the first MFMA.
// ---------------------------------------------------------------------------
template<int TAP>
__device__ __forceinline__ void metaA(int h, int w, u32 bb, u32 qoff, u32& abase) {
    constexpr int dh = TAP / 3 - 1, dw = TAP % 3 - 1;
    int hh = h + dh, ww = w + dw;
    bool valid = (hh >= 0) && (hh < H_) && (ww >= 0) && (ww < W_);
    u32 idx = valid ? (bb + (u32)(hh * W_ + ww)) : (u32)NPIX_;
    abase = (idx << 6) + qoff;
}

template<int SG>
__device__ __forceinline__ void mfma2(const u16* __restrict__ W27F, int lane,
                                      const bf16x8& sv, f32x4 (&acc)[2]) {
#pragma unroll
    for (int t = 0; t < 2; t++) {
        bf16x8 af = *(const bf16x8*)(W27F + (u32)((SG * 2 + t) * 64 + lane) * 8u);
        acc[t] = __builtin_amdgcn_mfma_f32_16x16x32_bf16(af, sv, acc[t], 0, 0, 0);
    }
}

template<int KH>
__device__ __forceinline__ void runA(const u16* __restrict__ xt,
                                     const u16* __restrict__ W27F,
                                     int h, int w, u32 bb, u32 qoff, int lane,
                                     f32x4 (&acc)[2]) {
    u32 a0, a1, a2;
    metaA<3 * KH + 0>(h, w, bb, qoff, a0);
    metaA<3 * KH + 1>(h, w, bb, qoff, a1);
    metaA<3 * KH + 2>(h, w, bb, qoff, a2);
    bf16x8 s0 = *(const bf16x8*)(xt + a0);
    bf16x8 s1 = *(const bf16x8*)(xt + a0 + 32);
    bf16x8 s2 = *(const bf16x8*)(xt + a1);
    bf16x8 s3 = *(const bf16x8*)(xt + a1 + 32);
    bf16x8 s4 = *(const bf16x8*)(xt + a2);
    bf16x8 s5 = *(const bf16x8*)(xt + a2 + 32);
    mfma2<6 * KH + 0>(W27F, lane, s0, acc);
    mfma2<6 * KH + 1>(W27F, lane, s1, acc);
    mfma2<6 * KH + 2>(W27F, lane, s2, acc);
    mfma2<6 * KH + 3>(W27F, lane, s3, acc);
    mfma2<6 * KH + 4>(W27F, lane, s4, acc);
    mfma2<6 * KH + 5>(W27F, lane, s5, acc);
}

// ---------------------------------------------------------------------------
// Phase B helpers (bilinear sampler GEMM). Meta from LDS (fp32); corner
// gathers run through an explicit depth-3 software pipeline.
// ---------------------------------------------------------------------------
template<int TAP>
__device__ __forceinline__ void metaB(const float* __restrict__ moff,
                                      const float* __restrict__ mmask,
                                      int p32, int h, int w, u32 bb, u32 qoff,
                                      u32 (&qc)[4], float (&cw)[4]) {
    float dy = moff[(2 * TAP) * 32 + p32];
    float dx = moff[(2 * TAP + 1) * 32 + p32];
    float m  = mmask[TAP * 32 + p32];
    constexpr float kdy = (float)(TAP / 3 - 1), kdx = (float)(TAP % 3 - 1);
    float py = dy + (float)h + kdy;
    float px = dx + (float)w + kdx;
    float y0 = floorf(py), x0 = floorf(px);
    float ly = py - y0, lx = px - x0, hy = 1.f - ly, hx = 1.f - lx;
    float y1 = y0 + 1.f, x1 = x0 + 1.f;
    bool vy0 = (y0 >= 0.f) && (y0 <= 127.f);
    bool vy1 = (y1 >= 0.f) && (y1 <= 127.f);
    bool vx0 = (x0 >= 0.f) && (x0 <= 127.f);
    bool vx1 = (x1 >= 0.f) && (x1 <= 127.f);
    int iy0 = (int)fminf(fmaxf(y0, 0.f), 127.f);
    int iy1 = (int)fminf(fmaxf(y1, 0.f), 127.f);
    int ix0 = (int)fminf(fmaxf(x0, 0.f), 127.f);
    int ix1 = (int)fminf(fmaxf(x1, 0.f), 127.f);
    qc[0] = ((bb + (u32)(iy0 * W_ + ix0)) << 6) + qoff; cw[0] = (vy0 && vx0) ? hy * hx * m : 0.f;
    qc[1] = ((bb + (u32)(iy0 * W_ + ix1)) << 6) + qoff; cw[1] = (vy0 && vx1) ? hy * lx * m : 0.f;
    qc[2] = ((bb + (u32)(iy1 * W_ + ix0)) << 6) + qoff; cw[2] = (vy1 && vx0) ? ly * hx * m : 0.f;
    qc[3] = ((bb + (u32)(iy1 * W_ + ix1)) << 6) + qoff; cw[3] = (vy1 && vx1) ? ly * lx * m : 0.f;
}

__device__ __forceinline__ void ld4(const u16* __restrict__ xt, const u32 (&qc)[4],
                                    u32 sc, uint4 (&p)[4]) {
#pragma unroll
    for (int i = 0; i < 4; i++) p[i] = *(const uint4*)(xt + qc[i] + sc);
}

__device__ __forceinline__ bf16x8 cmb(const uint4 (&p)[4], const float (&cw)[4]) {
    const u32* p0 = &p[0].x; const u32* p1 = &p[1].x;
    const u32* p2 = &p[2].x; const u32* p3 = &p[3].x;
    bf16x8 sv;
#pragma unroll
    for (int i = 0; i < 4; i++) {
        float lo = cw[0] * bflo(p0[i]) + cw[1] * bflo(p1[i])
                 + cw[2] * bflo(p2[i]) + cw[3] * bflo(p3[i]);
        float hi = cw[0] * bfhi(p0[i]) + cw[1] * bfhi(p1[i])
                 + cw[2] * bfhi(p2[i]) + cw[3] * bfhi(p3[i]);
        sv[2 * i]     = (short)f2bf(lo);
        sv[2 * i + 1] = (short)f2bf(hi);
    }
    return sv;
}

template<int SG>
__device__ __forceinline__ void mfma4(const u16* __restrict__ WpF, int lane,
                                      const bf16x8& sv, f32x4 (&acc)[4]) {
#pragma unroll
    for (int t = 0; t < 4; t++) {
        bf16x8 af = *(const bf16x8*)(WpF + (u32)((SG * 4 + t) * 64 + lane) * 8u);
        acc[t] = __builtin_amdgcn_mfma_f32_16x16x32_bf16(af, sv, acc[t], 0, 0, 0);
    }
}

template<int KH>
__device__ __forceinline__ void runB(const u16* __restrict__ xt,
                                     const float* __restrict__ moff,
                                     const float* __restrict__ mmask,
                                     const u16* __restrict__ WpF,
                                     int p32, int h, int w, u32 bb, u32 qoff,
                                     int lane, f32x4 (&acc)[4]) {
    u32 q0[4], q1[4], q2[4]; float w0[4], w1[4], w2[4];
    metaB<3 * KH + 0>(moff, mmask, p32, h, w, bb, qoff, q0, w0);
    metaB<3 * KH + 1>(moff, mmask, p32, h, w, bb, qoff, q1, w1);
    metaB<3 * KH + 2>(moff, mmask, p32, h, w, bb, qoff, q2, w2);
    uint4 pA[4], pB[4], pC[4];
    ld4(xt, q0, 0,  pA);
    ld4(xt, q0, 32, pB);
    ld4(xt, q1, 0,  pC);
    bf16x8 sv;
    sv = cmb(pA, w0); mfma4<6 * KH + 0>(WpF, lane, sv, acc); ld4(xt, q1, 32, pA);
    sv = cmb(pB, w0); mfma4<6 * KH + 1>(WpF, lane, sv, acc); ld4(xt, q2, 0,  pB);
    sv = cmb(pC, w1); mfma4<6 * KH + 2>(WpF, lane, sv, acc); ld4(xt, q2, 32, pC);
    sv = cmb(pA, w1); mfma4<6 * KH + 3>(WpF, lane, sv, acc);
    sv = cmb(pB, w2); mfma4<6 * KH + 4>(WpF, lane, sv, acc);
    sv = cmb(pC, w2); mfma4<6 * KH + 5>(WpF, lane, sv, acc);
}

// ---------------------------------------------------------------------------
// Fused GEMM-a + GEMM-b. Block = 32 pixels, 384 thr = 6 waves =
// (2 px-groups ph of 16) x (3 K-thirds kh). Phase A: offset/mask -> LDS fp32.
// Phase B: sampler GEMM (pipelined gathers). Epilogue: LDS reduce K-thirds,
// bf16 pre-out, per-block stats partials.
// ---------------------------------------------------------------------------
__global__ __launch_bounds__(384, 3)
void gemm_ab_kernel(const u16* __restrict__ xt, const u16* __restrict__ W27F,
                    const u16* __restrict__ WpF,
                    const float* __restrict__ off_b, const float* __restrict__ mask_b,
                    u16* __restrict__ pre16, float* __restrict__ part) {
    __shared__ float red[4][64][17];
    __shared__ float moff[18 * 32];
    __shared__ float mmask[9 * 32];
    const int tid = threadIdx.x;
    const int lane = tid & 63, wv = tid >> 6;
    const int ph = wv & 1, kh = wv >> 1;
    const int quad = lane >> 4, r = lane & 15;
    const int pbase = blockIdx.x * 32;
    const int b = pbase >> 14, hwb = pbase & (HW_ - 1);
    const int p32 = ph * 16 + r;
    const int hw = hwb + p32, h = hw >> 7, w = hw & (W_ - 1);
    const u32 bb = (u32)b << 14;
    const u32 qoff = (u32)quad * 8u;

    // ---------------- Phase A: offsets + mask into LDS ----------------
    {
        f32x4 acc[2];
        acc[0] = (f32x4){0.f, 0.f, 0.f, 0.f};
        acc[1] = (f32x4){0.f, 0.f, 0.f, 0.f};
        if (kh == 0)      runA<0>(xt, W27F, h, w, bb, qoff, lane, acc);
        else if (kh == 1) runA<1>(xt, W27F, h, w, bb, qoff, lane, acc);
        else              runA<2>(xt, W27F, h, w, bb, qoff, lane, acc);

        if (kh != 0) {
            int slot = (kh - 1) * 2 + ph;
#pragma unroll
            for (int t = 0; t < 2; t++)
#pragma unroll
                for (int g = 0; g < 4; g++) red[slot][lane][t * 4 + g] = acc[t][g];
        }
        __syncthreads();
        if (kh == 0) {
#pragma unroll
            for (int t = 0; t < 2; t++) {
#pragma unroll
                for (int g = 0; g < 4; g++) {
                    float v = acc[t][g] + red[ph][lane][t * 4 + g] + red[2 + ph][lane][t * 4 + g];
                    int o = t * 16 + quad * 4 + g;
                    if (o < 18) {
                        moff[o * 32 + p32] = v + off_b[o];
                    } else if (o < 27) {
                        v += mask_b[o - 18];
                        mmask[(o - 18) * 32 + p32] = 1.f / (1.f + __expf(-v));
                    }
                }
            }
        }
        __syncthreads();
    }

    // ---------------- Phase B: sampler GEMM ----------------
    f32x4 acc[4];
#pragma unroll
    for (int t = 0; t < 4; t++) acc[t] = (f32x4){0.f, 0.f, 0.f, 0.f};

    if (kh == 0)      runB<0>(xt, moff, mmask, WpF, p32, h, w, bb, qoff, lane, acc);
    else if (kh == 1) runB<1>(xt, moff, mmask, WpF, p32, h, w, bb, qoff, lane, acc);
    else              runB<2>(xt, moff, mmask, WpF, p32, h, w, bb, qoff, lane, acc);

    if (kh != 0) {
        int slot = (kh - 1) * 2 + ph;
#pragma unroll
        for (int t = 0; t < 4; t++)
#pragma unroll
            for (int g = 0; g < 4; g++) red[slot][lane][t * 4 + g] = acc[t][g];
    }
    __syncthreads();
    if (kh == 0) {
        const u32 slot = (u32)blockIdx.x * 2 + (u32)ph;
#pragma unroll
        for (int t = 0; t < 4; t++) {
#pragma unroll
            for (int g = 0; g < 4; g++) {
                float v = acc[t][g] + red[ph][lane][t * 4 + g] + red[2 + ph][lane][t * 4 + g];
                int o = t * 16 + quad * 4 + g;
                pre16[(u32)(b * 64 + o) * HW_ + hw] = f2bf(v);
                float s = v, s2 = v * v;
#pragma unroll
                for (int off = 8; off >= 1; off >>= 1) {
                    s  += __shfl_down(s, off, 16);
                    s2 += __shfl_down(s2, off, 16);
                }
                if (r == 0) {
                    part[(u32)o * 2048 + slot] = s;            // sums
                    part[131072 + (u32)o * 2048 + slot] = s2;  // sumsqs
                }
            }
        }
    }
}

// ---------------------------------------------------------------------------
// stats reduce: stats[i] (i<64 sum, i>=64 sumsq) = Σ over 2048 contiguous
// block-partials (coalesced).
// ---------------------------------------------------------------------------
__global__ __launch_bounds__(256)
void stats_red_kernel(const float* __restrict__ part, float* __restrict__ stats) {
    __shared__ float p4[4];
    int i = blockIdx.x;                       // 0..127
    const float* src = part + (u32)(i >> 6) * 131072 + (u32)(i & 63) * 2048;
    float s = 0.f;
    for (int rr = threadIdx.x; rr < 2048; rr += 256) s += src[rr];
#pragma unroll
    for (int off = 32; off >= 1; off >>= 1) s += __shfl_down(s, off);
    if ((threadIdx.x & 63) == 0) p4[threadIdx.x >> 6] = s;
    __syncthreads();
    if (threadIdx.x == 0) stats[i] = p4[0] + p4[1] + p4[2] + p4[3];
}

// ---------------------------------------------------------------------------
// BN apply + ReLU from bf16 pre-out.
// ---------------------------------------------------------------------------
__global__ __launch_bounds__(256)
void bn_relu_kernel(const u16* __restrict__ pre16, const float* __restrict__ stats,
                    const float* __restrict__ gamma, const float* __restrict__ beta,
                    float* __restrict__ out) {
    int i4 = blockIdx.x * 256 + threadIdx.x;   // 4-element group index
    int ch = (i4 >> 12) & (O_ - 1);
    float mean = stats[ch] * (1.f / NPIX_);
    float var  = stats[64 + ch] * (1.f / NPIX_) - mean * mean;
    float scale = gamma[ch] * rsqrtf(var + BN_EPS_);
    float shift = beta[ch] - mean * scale;
    uint2 v = ((const uint2*)pre16)[i4];
    float4 o;
    o.x = fmaxf(fmaf(bflo(v.x), scale, shift), 0.f);
    o.y = fmaxf(fmaf(bfhi(v.x), scale, shift), 0.f);
    o.z = fmaxf(fmaf(bflo(v.y), scale, shift), 0.f);
    o.w = fmaxf(fmaf(bfhi(v.y), scale, shift), 0.f);
    ((float4*)out)[i4] = o;
}

// ---------------------------------------------------------------------------
extern "C" void kernel_launch(void* const* d_in, const int* in_sizes, int n_in,
                              void* d_out, int out_size, void* d_ws, size_t ws_size,
                              hipStream_t stream) {
    const float* x      = (const float*)d_in[0];
    const float* conv_w = (const float*)d_in[1];
    const float* off_w  = (const float*)d_in[2];
    const float* off_b  = (const float*)d_in[3];
    const float* mask_w = (const float*)d_in[4];
    const float* mask_b = (const float*)d_in[5];
    const float* gamma  = (const float*)d_in[6];
    const float* beta   = (const float*)d_in[7];
    float* out = (float*)d_out;

    // workspace layout: 9,548,416 B total
    char* ws = (char*)d_ws;
    u16*  xt     = (u16*)(ws);                   // [2][16384][64] bf16 + 128B pad = 4,194,432
    u16*  pre16  = (u16*)(ws + 4194432);         // [2][64][16384] bf16 = 4,194,304
    u16*  WpF    = (u16*)(ws + 8388736);         // 36,864 el = 73,728
    u16*  W27F   = (u16*)(ws + 8462464);         // 18,432 el = 36,864
    float* part  = (float*)(ws + 8499328);       // 2 x [64][2048] f32 = 1,048,576
    float* stats = (float*)(ws + 9547904);       // 128 f32 = 512

    prep_kernel<<<729, 256, 0, stream>>>(x, conv_w, off_w, mask_w, xt, WpF, W27F);
    gemm_ab_kernel<<<NPIX_ / 32, 384, 0, stream>>>(xt, W27F, WpF, off_b, mask_b, pre16, part);
    stats_red_kernel<<<128, 256, 0, stream>>>(part, stats);
    bn_relu_kernel<<<2048, 256, 0, stream>>>(pre16, stats, gamma, beta, out);
}